// Round 1
// 899.064 us; speedup vs baseline: 1.1547x; 1.1547x over previous
//
#include <hip/hip_runtime.h>
#include <hip/hip_bf16.h>
#include <cstdint>
#include <cstddef>

#define BB 4
#define CC 192
#define NHEAD 6
#define WSZ 16
#define SSH 8
#define NTOK 256
#define HD 32
#define HWPIX 16384
#define TTOT 65536
#define WWID 128
#define SCALE_Q 0.17677669529663687f
#define CONV_SC 0.01f
#define PSTR 264   // LDS row stride (shorts): 16B-aligned, <=2-way banks
#define HSTR 784   // k_mlp h LDS row stride (shorts): 1568B -> +8 banks/row

typedef __hip_bfloat16 bf16;
typedef __attribute__((ext_vector_type(8))) short short8;
typedef __attribute__((ext_vector_type(4))) float float4v;

__device__ __forceinline__ float b2f(bf16 v) { return __bfloat162float(v); }
__device__ __forceinline__ bf16 f2b(float v) { return __float2bfloat16(v); }
__device__ __forceinline__ unsigned short f2bu(float f) {
  bf16 h = __float2bfloat16(f);
  return *reinterpret_cast<unsigned short*>(&h);
}
__device__ __forceinline__ float gelu_exact(float x) {
  return 0.5f * x * (1.0f + erff(x * 0.7071067811865475f));
}
__device__ __forceinline__ short8 ld8z(const bf16* p, bool ok) {
  if (ok) return *(const short8*)p;
  short8 z = {0, 0, 0, 0, 0, 0, 0, 0};
  return z;
}

// ---------------- K1: LayerNorm1 (x fp32 -> xn bf16). 1 wave per token -----
__global__ __launch_bounds__(256) void k_ln1(const float* __restrict__ x,
                                             const float* __restrict__ g,
                                             const float* __restrict__ b,
                                             bf16* __restrict__ xn) {
  int wv = threadIdx.x >> 6, lane = threadIdx.x & 63;
  int tok = blockIdx.x * 4 + wv;
  size_t row = (size_t)tok * CC;
  float v0 = x[row + lane], v1 = x[row + lane + 64], v2 = x[row + lane + 128];
  float s = v0 + v1 + v2, ss = v0 * v0 + v1 * v1 + v2 * v2;
#pragma unroll
  for (int off = 1; off < 64; off <<= 1) {
    s += __shfl_xor(s, off, 64);
    ss += __shfl_xor(ss, off, 64);
  }
  float mean = s * (1.0f / CC);
  float rstd = rsqrtf(ss * (1.0f / CC) - mean * mean + 1e-5f);
  xn[row + lane]       = f2b((v0 - mean) * rstd * g[lane]       + b[lane]);
  xn[row + lane + 64]  = f2b((v1 - mean) * rstd * g[lane + 64]  + b[lane + 64]);
  xn[row + lane + 128] = f2b((v2 - mean) * rstd * g[lane + 128] + b[lane + 128]);
}

// ------------- K2: bias gather biasQ[h][query][key] (fp32) ------------------
__global__ __launch_bounds__(256) void k_biasq(const int* __restrict__ rpi,
                                               const float* __restrict__ rpb,
                                               float* __restrict__ biasQ) {
  int k = threadIdx.x;
  int h = blockIdx.x >> 8;
  int q = blockIdx.x & 255;
  biasQ[(size_t)blockIdx.x * 256 + k] = rpb[rpi[q * 256 + k] * NHEAD + h];
}

// ------- K2b: conv weight transpose to [tap][oc][ci] bf16 -------------------
__global__ __launch_bounds__(256) void k_wprep(const float* __restrict__ c1w,
                                               const float* __restrict__ c2w,
                                               bf16* __restrict__ wT1,
                                               bf16* __restrict__ wT2) {
  int i = blockIdx.x * 256 + threadIdx.x;   // 0 .. 110591
  {
    int tap = i / (64 * 192); int r = i % (64 * 192);
    int oc = r / 192, ci = r % 192;
    wT1[i] = f2b(c1w[(size_t)(tap * 192 + ci) * 64 + oc]);
  }
  {
    int tap = i / (192 * 64); int r = i % (192 * 64);
    int oc = r / 64, ci = r % 64;
    wT2[i] = f2b(c2w[(size_t)(tap * 64 + ci) * 192 + oc]);
  }
}

// ------- K2c: MLP weight transpose to n-major bf16 --------------------------
__global__ __launch_bounds__(256) void k_wprep2(const float* __restrict__ fc1w,
                                                const float* __restrict__ fc2w,
                                                bf16* __restrict__ wF1,
                                                bf16* __restrict__ wF2) {
  int i = blockIdx.x * 256 + threadIdx.x;   // 0 .. 147455
  {
    int n = i / 192, k = i % 192;           // wF1[n][k], n<768 k<192
    wF1[i] = f2b(fc1w[(size_t)k * 768 + n]);
  }
  {
    int n = i / 768, k = i % 768;           // wF2[n][k], n<192 k<768
    wF2[i] = f2b(fc2w[(size_t)k * 192 + n]);
  }
}

// ------- K2d: qkv/proj weight transpose to n-major bf16 ---------------------
__global__ __launch_bounds__(256) void k_wprep3(const float* __restrict__ qkvw,
                                                const float* __restrict__ projw,
                                                bf16* __restrict__ wQv,
                                                bf16* __restrict__ wP) {
  int i = blockIdx.x * 256 + threadIdx.x;   // 0 .. 147455 (grid 576)
  if (i < 576 * 192) {
    int n = i / 192, k = i % 192;           // wQv[n][k], n<576
    wQv[i] = f2b(qkvw[(size_t)k * 576 + n]);
  }
  if (i < 192 * 192) {
    int n = i / 192, k = i % 192;           // wP[n][k]
    wP[i] = f2b(projw[(size_t)k * 192 + n]);
  }
}

// --- K3: QKV GEMM via MFMA (N=576, K=192), gathered scatter store -----------
// grid TTOT/16, block 256 (4 waves). Wave w: cols w*144..+143 (9 tiles).
__global__ __launch_bounds__(256) void k_qkvg2(const bf16* __restrict__ xn,
                                               const bf16* __restrict__ wQv,
                                               const float* __restrict__ qb,
                                               bf16* __restrict__ Qg,
                                               bf16* __restrict__ Kg,
                                               bf16* __restrict__ Vg) {
  int tok0 = blockIdx.x * 16;
  int wave = threadIdx.x >> 6, lane = threadIdx.x & 63;
  int lm = lane & 15, lq = lane >> 4;
  const bf16* arow = xn + (size_t)(tok0 + lm) * CC + lq * 8;
  float4v acc[9];
#pragma unroll
  for (int nt = 0; nt < 9; ++nt) acc[nt] = (float4v){0.f, 0.f, 0.f, 0.f};
#pragma unroll
  for (int ks = 0; ks < 6; ++ks) {
    short8 afrag = *(const short8*)(arow + ks * 32);
#pragma unroll
    for (int nt = 0; nt < 9; ++nt) {
      int col = wave * 144 + nt * 16 + lm;
      short8 bfrag = *(const short8*)(wQv + (size_t)col * CC + ks * 32 + lq * 8);
      acc[nt] = __builtin_amdgcn_mfma_f32_16x16x32_bf16(afrag, bfrag, acc[nt], 0, 0, 0);
    }
  }
  // per-reg token -> gathered (window,head) coords
  size_t base[4];
#pragma unroll
  for (int reg = 0; reg < 4; ++reg) {
    int tg = tok0 + lq * 4 + reg;
    int b = tg >> 14;
    int pix = tg & 16383;
    int gh = pix >> 7, gw = pix & 127;
    int hs = (gh + 120) & 127, wsx = (gw + 120) & 127;
    int wdx = (b << 6) + ((hs >> 4) << 3) + (wsx >> 4);
    int ndx = ((hs & 15) << 4) + (wsx & 15);
    base[reg] = ((size_t)wdx * NHEAD) * NTOK * HD + (size_t)ndx * HD;  // + head*NTOK*HD + d
  }
#pragma unroll
  for (int nt = 0; nt < 9; ++nt) {
    int col = wave * 144 + nt * 16 + lm;
    float bias = qb[col];
    int sect = col / 192, within = col - sect * 192;
    int head = within >> 5, d = within & 31;
    bf16* dst = (sect == 0) ? Qg : (sect == 1) ? Kg : Vg;
    float scale = (sect == 0) ? SCALE_Q : 1.f;
#pragma unroll
    for (int reg = 0; reg < 4; ++reg) {
      dst[base[reg] + (size_t)head * NTOK * HD + d] = f2b((acc[nt][reg] + bias) * scale);
    }
  }
}

// --- K4: windowed attention via MFMA --------------------------------------
// grid = 1536*2 (wh, query-half). block 256 = 4 waves x 32 queries.
// S = Q*K^T (MFMA), full softmax per 16-row tile, P->LDS bf16, O = P*V (MFMA).
__global__ __launch_bounds__(256) void k_attn2(const bf16* __restrict__ Qg,
                                               const bf16* __restrict__ Kg,
                                               const bf16* __restrict__ Vg,
                                               const float* __restrict__ biasQ,
                                               bf16* __restrict__ AO) {
  __shared__ unsigned short PTw[4][16 * PSTR];  // 33,792 B (wave-private P tiles)
  __shared__ unsigned short VT[32 * PSTR];      // 16,896 B (V transposed)
  int wh = blockIdx.x >> 1, half = blockIdx.x & 1;
  int wdx = wh / NHEAD, h = wh - wdx * NHEAD;
  int wl = wdx & 63;
  int wr = wl >> 3, wc = wl & 7;
  int tid = threadIdx.x;
  int wave = tid >> 6, lane = tid & 63;
  int lm = lane & 15, lq = lane >> 4;
  int q0 = half * 128;

  // stage V^T: thread tid handles key row tid
  {
    const uint4* vp = (const uint4*)(Vg + ((size_t)wh * NTOK + tid) * HD);
    uint4 vv[4] = {vp[0], vp[1], vp[2], vp[3]};
#pragma unroll
    for (int i = 0; i < 4; ++i) {
      unsigned arr[4] = {vv[i].x, vv[i].y, vv[i].z, vv[i].w};
#pragma unroll
      for (int j = 0; j < 4; ++j) {
        int d = i * 8 + j * 2;
        VT[d * PSTR + tid]       = (unsigned short)(arr[j] & 0xffffu);
        VT[(d + 1) * PSTR + tid] = (unsigned short)(arr[j] >> 16);
      }
    }
  }
  __syncthreads();

  int wsk = (wc << 4) + lm;                       // lane's key col (w coord)
  int ridk_w = (wsk >= 112) + (wsk >= 120);
  unsigned short* PT = &PTw[wave][0];

  float4v oacc[2][2];
#pragma unroll
  for (int rt = 0; rt < 2; ++rt)
#pragma unroll
    for (int c2 = 0; c2 < 2; ++c2) oacc[rt][c2] = (float4v){0.f, 0.f, 0.f, 0.f};
  float linv[2][4];

#pragma unroll
  for (int rt = 0; rt < 2; ++rt) {
    int qrow = q0 + wave * 32 + rt * 16;
    short8 aq = *(const short8*)(Qg + ((size_t)wh * NTOK + qrow + lm) * HD + lq * 8);
    float4v sacc[16];
#pragma unroll
    for (int ct = 0; ct < 16; ++ct) sacc[ct] = (float4v){0.f, 0.f, 0.f, 0.f};
#pragma unroll
    for (int ct = 0; ct < 16; ++ct) {
      short8 kf = *(const short8*)(Kg + ((size_t)wh * NTOK + ct * 16 + lm) * HD + lq * 8);
      sacc[ct] = __builtin_amdgcn_mfma_f32_16x16x32_bf16(aq, kf, sacc[ct], 0, 0, 0);
    }
    // softmax over 256 keys, rows lq*4+reg of this 16-row tile
#pragma unroll
    for (int reg = 0; reg < 4; ++reg) {
      int nq = qrow + lq * 4 + reg;
      int hsq = (wr << 4) + (nq >> 4), wsq = (wc << 4) + (nq & 15);
      int ridq = ((hsq >= 112) + (hsq >= 120)) * 3 + ((wsq >= 112) + (wsq >= 120));
      const float* bq = biasQ + ((size_t)(h * 256 + nq)) * 256 + lm;
      float sv[16];
      float mx = -1.0e30f;
#pragma unroll
      for (int ct = 0; ct < 16; ++ct) {
        int hsk = (wr << 4) + ct;
        int ridk = ((hsk >= 112) + (hsk >= 120)) * 3 + ridk_w;
        float s = sacc[ct][reg] + bq[ct * 16] + ((ridk != ridq) ? -100.f : 0.f);
        sv[ct] = s;
        mx = fmaxf(mx, s);
      }
#pragma unroll
      for (int off = 1; off < 16; off <<= 1) mx = fmaxf(mx, __shfl_xor(mx, off, 64));
      float l = 0.f;
#pragma unroll
      for (int ct = 0; ct < 16; ++ct) {
        float p = __expf(sv[ct] - mx);
        l += p;
        PT[(lq * 4 + reg) * PSTR + ct * 16 + lm] = f2bu(p);
      }
#pragma unroll
      for (int off = 1; off < 16; off <<= 1) l += __shfl_xor(l, off, 64);
      linv[rt][reg] = 1.f / l;
    }
    // PV for this row tile: A = P rows (wave-private, in-wave LDS ordering)
#pragma unroll
    for (int kb = 0; kb < 8; ++kb) {
      short8 pf = *(const short8*)&PT[lm * PSTR + kb * 32 + lq * 8];
#pragma unroll
      for (int c2 = 0; c2 < 2; ++c2) {
        short8 vf = *(const short8*)&VT[(c2 * 16 + lm) * PSTR + kb * 32 + lq * 8];
        oacc[rt][c2] = __builtin_amdgcn_mfma_f32_16x16x32_bf16(pf, vf, oacc[rt][c2], 0, 0, 0);
      }
    }
  }
  // write AO
#pragma unroll
  for (int rt = 0; rt < 2; ++rt)
#pragma unroll
    for (int c2 = 0; c2 < 2; ++c2) {
      int d = c2 * 16 + lm;
#pragma unroll
      for (int reg = 0; reg < 4; ++reg) {
        int nq = q0 + wave * 32 + rt * 16 + lq * 4 + reg;
        AO[((size_t)wdx * NTOK + nq) * CC + h * HD + d] =
            f2b(oacc[rt][c2][reg] * linv[rt][reg]);
      }
    }
}

// --- K5: proj GEMM via MFMA (N=192, K=192) + shift-reverse + x residual -----
// grid TTOT/16 (win-order rows), block 256 (4 waves). Wave w: cols w*48..+47.
__global__ __launch_bounds__(256) void k_proj2(const bf16* __restrict__ AO,
                                               const bf16* __restrict__ wP,
                                               const float* __restrict__ pb,
                                               const float* __restrict__ x,
                                               float* __restrict__ y) {
  int r0 = blockIdx.x * 16;
  int wave = threadIdx.x >> 6, lane = threadIdx.x & 63;
  int lm = lane & 15, lq = lane >> 4;
  const bf16* arow = AO + (size_t)(r0 + lm) * CC + lq * 8;
  float4v acc[3];
#pragma unroll
  for (int nt = 0; nt < 3; ++nt) acc[nt] = (float4v){0.f, 0.f, 0.f, 0.f};
#pragma unroll
  for (int ks = 0; ks < 6; ++ks) {
    short8 afrag = *(const short8*)(arow + ks * 32);
#pragma unroll
    for (int nt = 0; nt < 3; ++nt) {
      int col = wave * 48 + nt * 16 + lm;
      short8 bfrag = *(const short8*)(wP + (size_t)col * CC + ks * 32 + lq * 8);
      acc[nt] = __builtin_amdgcn_mfma_f32_16x16x32_bf16(afrag, bfrag, acc[nt], 0, 0, 0);
    }
  }
  size_t drow[4];
#pragma unroll
  for (int reg = 0; reg < 4; ++reg) {
    int r = r0 + lq * 4 + reg;
    int wdx = r >> 8, n = r & 255;
    int wb = wdx >> 6, wl = wdx & 63;
    int hs = ((wl >> 3) << 4) + (n >> 4);
    int wsx = ((wl & 7) << 4) + (n & 15);
    int gh = (hs + SSH) & 127, gw = (wsx + SSH) & 127;
    drow[reg] = ((size_t)wb * HWPIX + (size_t)gh * WWID + gw) * CC;
  }
#pragma unroll
  for (int nt = 0; nt < 3; ++nt) {
    int col = wave * 48 + nt * 16 + lm;
    float bias = pb[col];
#pragma unroll
    for (int reg = 0; reg < 4; ++reg) {
      y[drow[reg] + col] = x[drow[reg] + col] + acc[nt][reg] + bias;
    }
  }
}

// ---- K6: conv3x3 192->64 + GELU via MFMA implicit GEMM ---------------------
__global__ __launch_bounds__(256) void k_conv1m(const bf16* __restrict__ xn,
                                                const bf16* __restrict__ wT1,
                                                const float* __restrict__ c1b,
                                                bf16* __restrict__ cv1) {
  int bi = blockIdx.x;
  int seg = bi & 1, hh = (bi >> 1) & 127, b = bi >> 8;
  int px0 = seg * 64;
  int wave = threadIdx.x >> 6, lane = threadIdx.x & 63;
  int lm = lane & 15, lq = lane >> 4;
  int oc = wave * 16 + lm;
  float4v acc[4];
#pragma unroll
  for (int t = 0; t < 4; ++t) acc[t] = (float4v){0.f, 0.f, 0.f, 0.f};
#pragma unroll
  for (int tap = 0; tap < 9; ++tap) {
    int kh = tap / 3, kw = tap % 3;
    int gh = hh + kh - 1;
    bool rowok = ((unsigned)gh < 128u);
    const bf16* wrow = wT1 + ((size_t)tap * 64 + oc) * CC + lq * 8;
    const bf16* xrow = xn + ((size_t)b * HWPIX + (size_t)gh * WWID) * CC + lq * 8;
#pragma unroll
    for (int ks = 0; ks < 6; ++ks) {
      short8 bfrag = *(const short8*)(wrow + ks * 32);
#pragma unroll
      for (int t = 0; t < 4; ++t) {
        int px = px0 + t * 16 + lm + kw - 1;
        short8 afrag = ld8z(xrow + (size_t)px * CC + ks * 32,
                            rowok && ((unsigned)px < 128u));
        acc[t] = __builtin_amdgcn_mfma_f32_16x16x32_bf16(afrag, bfrag, acc[t], 0, 0, 0);
      }
    }
  }
  float bias = c1b[oc];
#pragma unroll
  for (int t = 0; t < 4; ++t) {
    int pxb = px0 + t * 16 + lq * 4;
    size_t base = ((size_t)b * HWPIX + (size_t)hh * WWID + pxb) * 64 + oc;
    cv1[base]       = f2b(gelu_exact(acc[t][0] + bias));
    cv1[base + 64]  = f2b(gelu_exact(acc[t][1] + bias));
    cv1[base + 128] = f2b(gelu_exact(acc[t][2] + bias));
    cv1[base + 192] = f2b(gelu_exact(acc[t][3] + bias));
  }
}

// ---- K7: conv3x3 64->192 + bias via MFMA implicit GEMM ---------------------
__global__ __launch_bounds__(256) void k_conv2m(const bf16* __restrict__ cv1,
                                                const bf16* __restrict__ wT2,
                                                const float* __restrict__ c2b,
                                                bf16* __restrict__ cv2) {
  int bi = blockIdx.x;
  int seg = bi & 1, hh = (bi >> 1) & 127, b = bi >> 8;
  int px0 = seg * 64;
  int wave = threadIdx.x >> 6, lane = threadIdx.x & 63;
  int lm = lane & 15, lq = lane >> 4;
  float4v acc[3][4];
#pragma unroll
  for (int nt = 0; nt < 3; ++nt)
#pragma unroll
    for (int t = 0; t < 4; ++t) acc[nt][t] = (float4v){0.f, 0.f, 0.f, 0.f};
#pragma unroll
  for (int tap = 0; tap < 9; ++tap) {
    int kh = tap / 3, kw = tap % 3;
    int gh = hh + kh - 1;
    bool rowok = ((unsigned)gh < 128u);
    const bf16* xrow = cv1 + ((size_t)b * HWPIX + (size_t)gh * WWID) * 64 + lq * 8;
#pragma unroll
    for (int ks = 0; ks < 2; ++ks) {
      short8 bfrag[3];
#pragma unroll
      for (int nt = 0; nt < 3; ++nt) {
        int oc = wave * 48 + nt * 16 + lm;
        bfrag[nt] = *(const short8*)(wT2 + ((size_t)tap * 192 + oc) * 64 + ks * 32 + lq * 8);
      }
#pragma unroll
      for (int t = 0; t < 4; ++t) {
        int px = px0 + t * 16 + lm + kw - 1;
        short8 afrag = ld8z(xrow + (size_t)px * 64 + ks * 32,
                            rowok && ((unsigned)px < 128u));
#pragma unroll
        for (int nt = 0; nt < 3; ++nt)
          acc[nt][t] = __builtin_amdgcn_mfma_f32_16x16x32_bf16(afrag, bfrag[nt], acc[nt][t], 0, 0, 0);
      }
    }
  }
#pragma unroll
  for (int nt = 0; nt < 3; ++nt) {
    int oc = wave * 48 + nt * 16 + lm;
    float bias = c2b[oc];
#pragma unroll
    for (int t = 0; t < 4; ++t) {
      int pxb = px0 + t * 16 + lq * 4;
      size_t base = ((size_t)b * HWPIX + (size_t)hh * WWID + pxb) * CC + oc;
      cv2[base]           = f2b(acc[nt][t][0] + bias);
      cv2[base + CC]      = f2b(acc[nt][t][1] + bias);
      cv2[base + 2 * CC]  = f2b(acc[nt][t][2] + bias);
      cv2[base + 3 * CC]  = f2b(acc[nt][t][3] + bias);
    }
  }
}

// ---------------- K8: global average pool (sum into pooled, pre-zeroed) ----
__global__ __launch_bounds__(256) void k_pool(const bf16* __restrict__ cv2,
                                              float* __restrict__ pooled) {
  __shared__ float sacc[CC];
  int t = threadIdx.x;
  if (t < CC) sacc[t] = 0.f;
  __syncthreads();
  int b = blockIdx.x >> 7;
  int pc = blockIdx.x & 127;
  const bf16* base = cv2 + (size_t)b * HWPIX * CC + (size_t)pc * 128 * CC;
  for (int it = 0; it < 96; ++it) {
    int e = it * 256 + t;
    atomicAdd(&sacc[e % CC], b2f(base[e]));
  }
  __syncthreads();
  if (t < CC) atomicAdd(&pooled[b * CC + t], sacc[t]);
}

// ---------------- K9: channel attention weights ----------------
__global__ __launch_bounds__(192) void k_ca(const float* __restrict__ pooled,
                                            const float* __restrict__ w1,
                                            const float* __restrict__ b1,
                                            const float* __restrict__ w2,
                                            const float* __restrict__ b2,
                                            float* __restrict__ ca) {
  __shared__ float pld[CC];
  __shared__ float t1[6];
  int t = threadIdx.x, b = blockIdx.x;
  pld[t] = pooled[b * CC + t] * (1.0f / HWPIX);
  __syncthreads();
  if (t < 6) {
    float s = b1[t];
    for (int c = 0; c < CC; ++c) s += pld[c] * w1[c * 6 + t];
    t1[t] = fmaxf(s, 0.f);
  }
  __syncthreads();
  float s = b2[t];
#pragma unroll
  for (int k = 0; k < 6; ++k) s += t1[k] * w2[k * CC + t];
  ca[b * CC + t] = 1.f / (1.f + __expf(-s));
}

// --- K10: LN2 with conv-branch fold: yn = LN(y + cv2*ca*0.01) bf16 ---------
__global__ __launch_bounds__(256) void k_ln2(const float* __restrict__ y,
                                             const bf16* __restrict__ cv2,
                                             const float* __restrict__ ca,
                                             const float* __restrict__ g2,
                                             const float* __restrict__ b2,
                                             bf16* __restrict__ yn) {
  int wv = threadIdx.x >> 6, lane = threadIdx.x & 63;
  int tok = blockIdx.x * 4 + wv;
  const float* cab = ca + (tok >> 14) * CC;
  size_t row = (size_t)tok * CC;
  float v0 = y[row + lane]       + b2f(cv2[row + lane])       * cab[lane]       * CONV_SC;
  float v1 = y[row + lane + 64]  + b2f(cv2[row + lane + 64])  * cab[lane + 64]  * CONV_SC;
  float v2 = y[row + lane + 128] + b2f(cv2[row + lane + 128]) * cab[lane + 128] * CONV_SC;
  float s = v0 + v1 + v2, ss = v0 * v0 + v1 * v1 + v2 * v2;
#pragma unroll
  for (int off = 1; off < 64; off <<= 1) {
    s += __shfl_xor(s, off, 64);
    ss += __shfl_xor(ss, off, 64);
  }
  float mean = s * (1.0f / CC);
  float rstd = rsqrtf(ss * (1.0f / CC) - mean * mean + 1e-5f);
  yn[row + lane]       = f2b((v0 - mean) * rstd * g2[lane]       + b2[lane]);
  yn[row + lane + 64]  = f2b((v1 - mean) * rstd * g2[lane + 64]  + b2[lane + 64]);
  yn[row + lane + 128] = f2b((v2 - mean) * rstd * g2[lane + 128] + b2[lane + 128]);
}

// --- K11: fused MLP. grid TTOT/32, block 256 (4 waves). --------------------
// Phase 1 (fc1+GELU): swapped-operand MFMA (A=wF1 rows -> C rows are 4
// consecutive output channels per lane) so GELU output packs to ds_write_b64
// into h LDS [32 tok][HSTR]. HSTR=784 shorts => row stride 392 dwords = +8
// banks/row => conflict-free b64 writes and b128 reads.
// Phase 2 (fc2+residual): A=h rows from LDS, B=wF2 (L2-resident), epilogue
// identical to old k_fc2. h never touches HBM (was 200 MB round-trip).
__global__ __launch_bounds__(256) void k_mlp(const bf16* __restrict__ yn,
                                             const bf16* __restrict__ wF1,
                                             const bf16* __restrict__ wF2,
                                             const float* __restrict__ fb1,
                                             const float* __restrict__ fb2,
                                             const float* __restrict__ y,
                                             const bf16* __restrict__ cv2,
                                             const float* __restrict__ ca,
                                             float* __restrict__ out) {
  __shared__ unsigned short hl[32 * HSTR];   // 50,176 B
  int tok0 = blockIdx.x * 32;
  int wave = threadIdx.x >> 6, lane = threadIdx.x & 63;
  int lm = lane & 15, lq = lane >> 4;

  // ---- phase 1: h = GELU(yn @ fc1 + b), written transposed-free via swap ---
#pragma unroll
  for (int p = 0; p < 2; ++p) {
    float4v acc[2][6];
#pragma unroll
    for (int tt = 0; tt < 2; ++tt)
#pragma unroll
      for (int nt = 0; nt < 6; ++nt) acc[tt][nt] = (float4v){0.f, 0.f, 0.f, 0.f};
#pragma unroll
    for (int ks = 0; ks < 6; ++ks) {
      short8 bf0 = *(const short8*)(yn + (size_t)(tok0 + lm) * CC + ks * 32 + lq * 8);
      short8 bf1 = *(const short8*)(yn + (size_t)(tok0 + 16 + lm) * CC + ks * 32 + lq * 8);
#pragma unroll
      for (int nt = 0; nt < 6; ++nt) {
        int n = wave * 192 + p * 96 + nt * 16 + lm;
        short8 af = *(const short8*)(wF1 + (size_t)n * CC + ks * 32 + lq * 8);
        acc[0][nt] = __builtin_amdgcn_mfma_f32_16x16x32_bf16(af, bf0, acc[0][nt], 0, 0, 0);
        acc[1][nt] = __builtin_amdgcn_mfma_f32_16x16x32_bf16(af, bf1, acc[1][nt], 0, 0, 0);
      }
    }
#pragma unroll
    for (int nt = 0; nt < 6; ++nt) {
      int n0 = wave * 192 + p * 96 + nt * 16 + lq * 4;   // 4 consecutive channels
      float4 b4 = *(const float4*)(fb1 + n0);
#pragma unroll
      for (int tt = 0; tt < 2; ++tt) {
        unsigned short u0 = f2bu(gelu_exact(acc[tt][nt][0] + b4.x));
        unsigned short u1 = f2bu(gelu_exact(acc[tt][nt][1] + b4.y));
        unsigned short u2 = f2bu(gelu_exact(acc[tt][nt][2] + b4.z));
        unsigned short u3 = f2bu(gelu_exact(acc[tt][nt][3] + b4.w));
        uint2 pk;
        pk.x = (unsigned)u0 | ((unsigned)u1 << 16);
        pk.y = (unsigned)u2 | ((unsigned)u3 << 16);
        *(uint2*)&hl[(size_t)(tt * 16 + lm) * HSTR + n0] = pk;
      }
    }
  }
  __syncthreads();

  // ---- phase 2: out = h @ fc2 + (y + cv2*ca*0.01) + b ----
  float4v acc2[2][3];
#pragma unroll
  for (int tt = 0; tt < 2; ++tt)
#pragma unroll
    for (int nt = 0; nt < 3; ++nt) acc2[tt][nt] = (float4v){0.f, 0.f, 0.f, 0.f};
#pragma unroll
  for (int ks = 0; ks < 24; ++ks) {
    short8 h0 = *(const short8*)&hl[(size_t)lm * HSTR + ks * 32 + lq * 8];
    short8 h1 = *(const short8*)&hl[(size_t)(16 + lm) * HSTR + ks * 32 + lq * 8];
#pragma unroll
    for (int nt = 0; nt < 3; ++nt) {
      int col = wave * 48 + nt * 16 + lm;
      short8 wf = *(const short8*)(wF2 + (size_t)col * 768 + ks * 32 + lq * 8);
      acc2[0][nt] = __builtin_amdgcn_mfma_f32_16x16x32_bf16(h0, wf, acc2[0][nt], 0, 0, 0);
      acc2[1][nt] = __builtin_amdgcn_mfma_f32_16x16x32_bf16(h1, wf, acc2[1][nt], 0, 0, 0);
    }
  }
  const float* cab = ca + (tok0 >> 14) * CC;
#pragma unroll
  for (int tt = 0; tt < 2; ++tt)
#pragma unroll
    for (int nt = 0; nt < 3; ++nt) {
      int col = wave * 48 + nt * 16 + lm;
      float bias = fb2[col];
      float cas = cab[col] * CONV_SC;
#pragma unroll
      for (int reg = 0; reg < 4; ++reg) {
        int tok = tok0 + tt * 16 + lq * 4 + reg;
        size_t idx = (size_t)tok * CC + col;
        out[idx] = y[idx] + b2f(cv2[idx]) * cas + acc2[tt][nt][reg] + bias;
      }
    }
}

extern "C" void kernel_launch(void* const* d_in, const int* in_sizes, int n_in,
                              void* d_out, int out_size, void* d_ws, size_t ws_size,
                              hipStream_t stream) {
  const float* x      = (const float*)d_in[0];
  const float* qkv_w  = (const float*)d_in[1];
  const float* qkv_b  = (const float*)d_in[2];
  const float* proj_w = (const float*)d_in[3];
  const float* proj_b = (const float*)d_in[4];
  const float* rpb    = (const float*)d_in[5];
  const float* n1w    = (const float*)d_in[6];
  const float* n1b    = (const float*)d_in[7];
  const float* n2w    = (const float*)d_in[8];
  const float* n2b    = (const float*)d_in[9];
  const float* c1w    = (const float*)d_in[10];
  const float* c1b    = (const float*)d_in[11];
  const float* c2w    = (const float*)d_in[12];
  const float* c2b    = (const float*)d_in[13];
  const float* ca1w   = (const float*)d_in[14];
  const float* ca1b   = (const float*)d_in[15];
  const float* ca2w   = (const float*)d_in[16];
  const float* ca2b   = (const float*)d_in[17];
  const float* fc1w   = (const float*)d_in[18];
  const float* fc1b   = (const float*)d_in[19];
  const float* fc2w   = (const float*)d_in[20];
  const float* fc2b   = (const float*)d_in[21];
  const int*   rpi    = (const int*)d_in[22];
  (void)in_sizes; (void)n_in; (void)out_size; (void)ws_size;

  // ---- workspace layout: peak ~212.6 MB (< 256 MiB) ----
  char* wsb = (char*)d_ws;
  bf16*  xn    = (bf16*)(wsb + 0);            // 25,165,824
  bf16*  yn    = (bf16*)(wsb + 0);            // alias xn (dead after conv1m)
  float* biasQ = (float*)(wsb + 25165824);    //  1,572,864
  bf16*  Qg    = (bf16*)(wsb + 26738688);     // 25,165,824
  bf16*  Kg    = (bf16*)(wsb + 51904512);     // 25,165,824
  bf16*  Vg    = (bf16*)(wsb + 77070336);     // 25,165,824
  bf16*  AO    = (bf16*)(wsb + 102236160);    // 25,165,824
  float* y     = (float*)(wsb + 127401984);   // 50,331,648
  bf16*  cv1   = (bf16*)(wsb + 177733632);    //  8,388,608
  bf16*  cv2   = (bf16*)(wsb + 186122240);    // 25,165,824
  float* pool  = (float*)(wsb + 211288064);   //      3,072
  float* cavec = (float*)(wsb + 211291136);   //      3,072
  bf16*  wT1   = (bf16*)(wsb + 211294208);    //    221,184  [9][64][192]
  bf16*  wT2   = (bf16*)(wsb + 211515392);    //    221,184  [9][192][64]
  bf16*  wF1   = (bf16*)(wsb + 211736576);    //    294,912  [768][192]
  bf16*  wF2   = (bf16*)(wsb + 212031488);    //    294,912  [192][768]
  bf16*  wQv   = (bf16*)(wsb + 212326400);    //    221,184  [576][192]
  bf16*  wP    = (bf16*)(wsb + 212547584);    //     73,728  [192][192]
  float* out   = (float*)d_out;               // end 212,621,312

  k_ln1<<<TTOT / 4, 256, 0, stream>>>(x, n1w, n1b, xn);
  k_biasq<<<NHEAD * NTOK, 256, 0, stream>>>(rpi, rpb, biasQ);
  k_wprep<<<432, 256, 0, stream>>>(c1w, c2w, wT1, wT2);
  k_wprep2<<<576, 256, 0, stream>>>(fc1w, fc2w, wF1, wF2);
  k_wprep3<<<576, 256, 0, stream>>>(qkv_w, proj_w, wQv, wP);
  k_qkvg2<<<TTOT / 16, 256, 0, stream>>>(xn, wQv, qkv_b, Qg, Kg, Vg);
  k_attn2<<<BB * 64 * NHEAD * 2, 256, 0, stream>>>(Qg, Kg, Vg, biasQ, AO);
  k_proj2<<<TTOT / 16, 256, 0, stream>>>(AO, wP, proj_b, x, y);
  k_conv1m<<<1024, 256, 0, stream>>>(xn, wT1, c1b, cv1);
  k_conv2m<<<1024, 256, 0, stream>>>(cv1, wT2, c2b, cv2);
  hipMemsetAsync(pool, 0, BB * CC * sizeof(float), stream);
  k_pool<<<512, 256, 0, stream>>>(cv2, pool);
  k_ca<<<BB, 192, 0, stream>>>(pool, ca1w, ca1b, ca2w, ca2b, cavec);
  k_ln2<<<TTOT / 4, 256, 0, stream>>>(y, cv2, cavec, n2w, n2b, yn);
  k_mlp<<<TTOT / 32, 256, 0, stream>>>(yn, wF1, wF2, fc1b, fc2b, y, cv2, cavec, out);
}

// Round 2
// 881.556 us; speedup vs baseline: 1.1777x; 1.0199x over previous
//
#include <hip/hip_runtime.h>
#include <hip/hip_bf16.h>
#include <cstdint>
#include <cstddef>

#define BB 4
#define CC 192
#define NHEAD 6
#define WSZ 16
#define SSH 8
#define NTOK 256
#define HD 32
#define HWPIX 16384
#define TTOT 65536
#define WWID 128
#define SCALE_Q 0.17677669529663687f
#define CONV_SC 0.01f
#define PSTR 264   // attn LDS row stride (shorts): 16B-aligned, <=2-way banks
#define HSTR 776   // k_mlp h LDS row stride (shorts): 388 dw == 4 mod 32 -> all 8 bank-groups
#define YSTR 200   // k_mlp ynl row stride (shorts)

typedef __hip_bfloat16 bf16;
typedef __attribute__((ext_vector_type(8))) short short8;
typedef __attribute__((ext_vector_type(4))) float float4v;

__device__ __forceinline__ float b2f(bf16 v) { return __bfloat162float(v); }
__device__ __forceinline__ bf16 f2b(float v) { return __float2bfloat16(v); }
__device__ __forceinline__ unsigned short f2bu(float f) {
  bf16 h = __float2bfloat16(f);
  return *reinterpret_cast<unsigned short*>(&h);
}
__device__ __forceinline__ float gelu_exact(float x) {
  return 0.5f * x * (1.0f + erff(x * 0.7071067811865475f));
}
__device__ __forceinline__ short8 ld8z(const bf16* p, bool ok) {
  if (ok) return *(const short8*)p;
  short8 z = {0, 0, 0, 0, 0, 0, 0, 0};
  return z;
}

// ---------------- K1: LayerNorm1 (x fp32 -> xn bf16). 1 wave per token -----
__global__ __launch_bounds__(256) void k_ln1(const float* __restrict__ x,
                                             const float* __restrict__ g,
                                             const float* __restrict__ b,
                                             bf16* __restrict__ xn) {
  int wv = threadIdx.x >> 6, lane = threadIdx.x & 63;
  int tok = blockIdx.x * 4 + wv;
  size_t row = (size_t)tok * CC;
  float v0 = x[row + lane], v1 = x[row + lane + 64], v2 = x[row + lane + 128];
  float s = v0 + v1 + v2, ss = v0 * v0 + v1 * v1 + v2 * v2;
#pragma unroll
  for (int off = 1; off < 64; off <<= 1) {
    s += __shfl_xor(s, off, 64);
    ss += __shfl_xor(ss, off, 64);
  }
  float mean = s * (1.0f / CC);
  float rstd = rsqrtf(ss * (1.0f / CC) - mean * mean + 1e-5f);
  xn[row + lane]       = f2b((v0 - mean) * rstd * g[lane]       + b[lane]);
  xn[row + lane + 64]  = f2b((v1 - mean) * rstd * g[lane + 64]  + b[lane + 64]);
  xn[row + lane + 128] = f2b((v2 - mean) * rstd * g[lane + 128] + b[lane + 128]);
}

// ------------- K2: bias gather biasQ[h][query][key] (fp32) ------------------
__global__ __launch_bounds__(256) void k_biasq(const int* __restrict__ rpi,
                                               const float* __restrict__ rpb,
                                               float* __restrict__ biasQ) {
  int k = threadIdx.x;
  int h = blockIdx.x >> 8;
  int q = blockIdx.x & 255;
  biasQ[(size_t)blockIdx.x * 256 + k] = rpb[rpi[q * 256 + k] * NHEAD + h];
}

// ------- K2b: conv weight transpose to [tap][oc][ci] bf16 -------------------
__global__ __launch_bounds__(256) void k_wprep(const float* __restrict__ c1w,
                                               const float* __restrict__ c2w,
                                               bf16* __restrict__ wT1,
                                               bf16* __restrict__ wT2) {
  int i = blockIdx.x * 256 + threadIdx.x;   // 0 .. 110591
  {
    int tap = i / (64 * 192); int r = i % (64 * 192);
    int oc = r / 192, ci = r % 192;
    wT1[i] = f2b(c1w[(size_t)(tap * 192 + ci) * 64 + oc]);
  }
  {
    int tap = i / (192 * 64); int r = i % (192 * 64);
    int oc = r / 64, ci = r % 64;
    wT2[i] = f2b(c2w[(size_t)(tap * 64 + ci) * 192 + oc]);
  }
}

// ------- K2c: MLP weight transpose to n-major bf16 --------------------------
__global__ __launch_bounds__(256) void k_wprep2(const float* __restrict__ fc1w,
                                                const float* __restrict__ fc2w,
                                                bf16* __restrict__ wF1,
                                                bf16* __restrict__ wF2) {
  int i = blockIdx.x * 256 + threadIdx.x;   // 0 .. 147455
  {
    int n = i / 192, k = i % 192;           // wF1[n][k], n<768 k<192
    wF1[i] = f2b(fc1w[(size_t)k * 768 + n]);
  }
  {
    int n = i / 768, k = i % 768;           // wF2[n][k], n<192 k<768
    wF2[i] = f2b(fc2w[(size_t)k * 192 + n]);
  }
}

// ------- K2d: qkv/proj weight transpose to n-major bf16 ---------------------
__global__ __launch_bounds__(256) void k_wprep3(const float* __restrict__ qkvw,
                                                const float* __restrict__ projw,
                                                bf16* __restrict__ wQv,
                                                bf16* __restrict__ wP) {
  int i = blockIdx.x * 256 + threadIdx.x;   // 0 .. 147455 (grid 576)
  if (i < 576 * 192) {
    int n = i / 192, k = i % 192;           // wQv[n][k], n<576
    wQv[i] = f2b(qkvw[(size_t)k * 576 + n]);
  }
  if (i < 192 * 192) {
    int n = i / 192, k = i % 192;           // wP[n][k]
    wP[i] = f2b(projw[(size_t)k * 192 + n]);
  }
}

// --- K3: QKV GEMM via MFMA (N=576, K=192), gathered scatter store -----------
// grid TTOT/16, block 256 (4 waves). Wave w: cols w*144..+143 (9 tiles).
__global__ __launch_bounds__(256) void k_qkvg2(const bf16* __restrict__ xn,
                                               const bf16* __restrict__ wQv,
                                               const float* __restrict__ qb,
                                               bf16* __restrict__ Qg,
                                               bf16* __restrict__ Kg,
                                               bf16* __restrict__ Vg) {
  int tok0 = blockIdx.x * 16;
  int wave = threadIdx.x >> 6, lane = threadIdx.x & 63;
  int lm = lane & 15, lq = lane >> 4;
  const bf16* arow = xn + (size_t)(tok0 + lm) * CC + lq * 8;
  float4v acc[9];
#pragma unroll
  for (int nt = 0; nt < 9; ++nt) acc[nt] = (float4v){0.f, 0.f, 0.f, 0.f};
#pragma unroll
  for (int ks = 0; ks < 6; ++ks) {
    short8 afrag = *(const short8*)(arow + ks * 32);
#pragma unroll
    for (int nt = 0; nt < 9; ++nt) {
      int col = wave * 144 + nt * 16 + lm;
      short8 bfrag = *(const short8*)(wQv + (size_t)col * CC + ks * 32 + lq * 8);
      acc[nt] = __builtin_amdgcn_mfma_f32_16x16x32_bf16(afrag, bfrag, acc[nt], 0, 0, 0);
    }
  }
  // per-reg token -> gathered (window,head) coords
  size_t base[4];
#pragma unroll
  for (int reg = 0; reg < 4; ++reg) {
    int tg = tok0 + lq * 4 + reg;
    int b = tg >> 14;
    int pix = tg & 16383;
    int gh = pix >> 7, gw = pix & 127;
    int hs = (gh + 120) & 127, wsx = (gw + 120) & 127;
    int wdx = (b << 6) + ((hs >> 4) << 3) + (wsx >> 4);
    int ndx = ((hs & 15) << 4) + (wsx & 15);
    base[reg] = ((size_t)wdx * NHEAD) * NTOK * HD + (size_t)ndx * HD;  // + head*NTOK*HD + d
  }
#pragma unroll
  for (int nt = 0; nt < 9; ++nt) {
    int col = wave * 144 + nt * 16 + lm;
    float bias = qb[col];
    int sect = col / 192, within = col - sect * 192;
    int head = within >> 5, d = within & 31;
    bf16* dst = (sect == 0) ? Qg : (sect == 1) ? Kg : Vg;
    float scale = (sect == 0) ? SCALE_Q : 1.f;
#pragma unroll
    for (int reg = 0; reg < 4; ++reg) {
      dst[base[reg] + (size_t)head * NTOK * HD + d] = f2b((acc[nt][reg] + bias) * scale);
    }
  }
}

// --- K4: windowed attention via MFMA --------------------------------------
// grid = 1536*2 (wh, query-half). block 256 = 4 waves x 32 queries.
// S = Q*K^T (MFMA), full softmax per 16-row tile, P->LDS bf16, O = P*V (MFMA).
__global__ __launch_bounds__(256) void k_attn2(const bf16* __restrict__ Qg,
                                               const bf16* __restrict__ Kg,
                                               const bf16* __restrict__ Vg,
                                               const float* __restrict__ biasQ,
                                               bf16* __restrict__ AO) {
  __shared__ unsigned short PTw[4][16 * PSTR];  // 33,792 B (wave-private P tiles)
  __shared__ unsigned short VT[32 * PSTR];      // 16,896 B (V transposed)
  int wh = blockIdx.x >> 1, half = blockIdx.x & 1;
  int wdx = wh / NHEAD, h = wh - wdx * NHEAD;
  int wl = wdx & 63;
  int wr = wl >> 3, wc = wl & 7;
  int tid = threadIdx.x;
  int wave = tid >> 6, lane = tid & 63;
  int lm = lane & 15, lq = lane >> 4;
  int q0 = half * 128;

  // stage V^T: thread tid handles key row tid
  {
    const uint4* vp = (const uint4*)(Vg + ((size_t)wh * NTOK + tid) * HD);
    uint4 vv[4] = {vp[0], vp[1], vp[2], vp[3]};
#pragma unroll
    for (int i = 0; i < 4; ++i) {
      unsigned arr[4] = {vv[i].x, vv[i].y, vv[i].z, vv[i].w};
#pragma unroll
      for (int j = 0; j < 4; ++j) {
        int d = i * 8 + j * 2;
        VT[d * PSTR + tid]       = (unsigned short)(arr[j] & 0xffffu);
        VT[(d + 1) * PSTR + tid] = (unsigned short)(arr[j] >> 16);
      }
    }
  }
  __syncthreads();

  int wsk = (wc << 4) + lm;                       // lane's key col (w coord)
  int ridk_w = (wsk >= 112) + (wsk >= 120);
  unsigned short* PT = &PTw[wave][0];

  float4v oacc[2][2];
#pragma unroll
  for (int rt = 0; rt < 2; ++rt)
#pragma unroll
    for (int c2 = 0; c2 < 2; ++c2) oacc[rt][c2] = (float4v){0.f, 0.f, 0.f, 0.f};
  float linv[2][4];

#pragma unroll
  for (int rt = 0; rt < 2; ++rt) {
    int qrow = q0 + wave * 32 + rt * 16;
    short8 aq = *(const short8*)(Qg + ((size_t)wh * NTOK + qrow + lm) * HD + lq * 8);
    float4v sacc[16];
#pragma unroll
    for (int ct = 0; ct < 16; ++ct) sacc[ct] = (float4v){0.f, 0.f, 0.f, 0.f};
#pragma unroll
    for (int ct = 0; ct < 16; ++ct) {
      short8 kf = *(const short8*)(Kg + ((size_t)wh * NTOK + ct * 16 + lm) * HD + lq * 8);
      sacc[ct] = __builtin_amdgcn_mfma_f32_16x16x32_bf16(aq, kf, sacc[ct], 0, 0, 0);
    }
    // softmax over 256 keys, rows lq*4+reg of this 16-row tile
#pragma unroll
    for (int reg = 0; reg < 4; ++reg) {
      int nq = qrow + lq * 4 + reg;
      int hsq = (wr << 4) + (nq >> 4), wsq = (wc << 4) + (nq & 15);
      int ridq = ((hsq >= 112) + (hsq >= 120)) * 3 + ((wsq >= 112) + (wsq >= 120));
      const float* bq = biasQ + ((size_t)(h * 256 + nq)) * 256 + lm;
      float sv[16];
      float mx = -1.0e30f;
#pragma unroll
      for (int ct = 0; ct < 16; ++ct) {
        int hsk = (wr << 4) + ct;
        int ridk = ((hsk >= 112) + (hsk >= 120)) * 3 + ridk_w;
        float s = sacc[ct][reg] + bq[ct * 16] + ((ridk != ridq) ? -100.f : 0.f);
        sv[ct] = s;
        mx = fmaxf(mx, s);
      }
#pragma unroll
      for (int off = 1; off < 16; off <<= 1) mx = fmaxf(mx, __shfl_xor(mx, off, 64));
      float l = 0.f;
#pragma unroll
      for (int ct = 0; ct < 16; ++ct) {
        float p = __expf(sv[ct] - mx);
        l += p;
        PT[(lq * 4 + reg) * PSTR + ct * 16 + lm] = f2bu(p);
      }
#pragma unroll
      for (int off = 1; off < 16; off <<= 1) l += __shfl_xor(l, off, 64);
      linv[rt][reg] = 1.f / l;
    }
    // PV for this row tile: A = P rows (wave-private, in-wave LDS ordering)
#pragma unroll
    for (int kb = 0; kb < 8; ++kb) {
      short8 pf = *(const short8*)&PT[lm * PSTR + kb * 32 + lq * 8];
#pragma unroll
      for (int c2 = 0; c2 < 2; ++c2) {
        short8 vf = *(const short8*)&VT[(c2 * 16 + lm) * PSTR + kb * 32 + lq * 8];
        oacc[rt][c2] = __builtin_amdgcn_mfma_f32_16x16x32_bf16(pf, vf, oacc[rt][c2], 0, 0, 0);
      }
    }
  }
  // write AO
#pragma unroll
  for (int rt = 0; rt < 2; ++rt)
#pragma unroll
    for (int c2 = 0; c2 < 2; ++c2) {
      int d = c2 * 16 + lm;
#pragma unroll
      for (int reg = 0; reg < 4; ++reg) {
        int nq = q0 + wave * 32 + rt * 16 + lq * 4 + reg;
        AO[((size_t)wdx * NTOK + nq) * CC + h * HD + d] =
            f2b(oacc[rt][c2][reg] * linv[rt][reg]);
      }
    }
}

// --- K5: proj GEMM via MFMA (N=192, K=192) + shift-reverse + x residual -----
// grid TTOT/16 (win-order rows), block 256 (4 waves). Wave w: cols w*48..+47.
__global__ __launch_bounds__(256) void k_proj2(const bf16* __restrict__ AO,
                                               const bf16* __restrict__ wP,
                                               const float* __restrict__ pb,
                                               const float* __restrict__ x,
                                               float* __restrict__ y) {
  int r0 = blockIdx.x * 16;
  int wave = threadIdx.x >> 6, lane = threadIdx.x & 63;
  int lm = lane & 15, lq = lane >> 4;
  const bf16* arow = AO + (size_t)(r0 + lm) * CC + lq * 8;
  float4v acc[3];
#pragma unroll
  for (int nt = 0; nt < 3; ++nt) acc[nt] = (float4v){0.f, 0.f, 0.f, 0.f};
#pragma unroll
  for (int ks = 0; ks < 6; ++ks) {
    short8 afrag = *(const short8*)(arow + ks * 32);
#pragma unroll
    for (int nt = 0; nt < 3; ++nt) {
      int col = wave * 48 + nt * 16 + lm;
      short8 bfrag = *(const short8*)(wP + (size_t)col * CC + ks * 32 + lq * 8);
      acc[nt] = __builtin_amdgcn_mfma_f32_16x16x32_bf16(afrag, bfrag, acc[nt], 0, 0, 0);
    }
  }
  size_t drow[4];
#pragma unroll
  for (int reg = 0; reg < 4; ++reg) {
    int r = r0 + lq * 4 + reg;
    int wdx = r >> 8, n = r & 255;
    int wb = wdx >> 6, wl = wdx & 63;
    int hs = ((wl >> 3) << 4) + (n >> 4);
    int wsx = ((wl & 7) << 4) + (n & 15);
    int gh = (hs + SSH) & 127, gw = (wsx + SSH) & 127;
    drow[reg] = ((size_t)wb * HWPIX + (size_t)gh * WWID + gw) * CC;
  }
#pragma unroll
  for (int nt = 0; nt < 3; ++nt) {
    int col = wave * 48 + nt * 16 + lm;
    float bias = pb[col];
#pragma unroll
    for (int reg = 0; reg < 4; ++reg) {
      y[drow[reg] + col] = x[drow[reg] + col] + acc[nt][reg] + bias;
    }
  }
}

// ---- K6: conv3x3 192->64 + GELU via MFMA implicit GEMM ---------------------
__global__ __launch_bounds__(256) void k_conv1m(const bf16* __restrict__ xn,
                                                const bf16* __restrict__ wT1,
                                                const float* __restrict__ c1b,
                                                bf16* __restrict__ cv1) {
  int bi = blockIdx.x;
  int seg = bi & 1, hh = (bi >> 1) & 127, b = bi >> 8;
  int px0 = seg * 64;
  int wave = threadIdx.x >> 6, lane = threadIdx.x & 63;
  int lm = lane & 15, lq = lane >> 4;
  int oc = wave * 16 + lm;
  float4v acc[4];
#pragma unroll
  for (int t = 0; t < 4; ++t) acc[t] = (float4v){0.f, 0.f, 0.f, 0.f};
#pragma unroll
  for (int tap = 0; tap < 9; ++tap) {
    int kh = tap / 3, kw = tap % 3;
    int gh = hh + kh - 1;
    bool rowok = ((unsigned)gh < 128u);
    const bf16* wrow = wT1 + ((size_t)tap * 64 + oc) * CC + lq * 8;
    const bf16* xrow = xn + ((size_t)b * HWPIX + (size_t)gh * WWID) * CC + lq * 8;
#pragma unroll
    for (int ks = 0; ks < 6; ++ks) {
      short8 bfrag = *(const short8*)(wrow + ks * 32);
#pragma unroll
      for (int t = 0; t < 4; ++t) {
        int px = px0 + t * 16 + lm + kw - 1;
        short8 afrag = ld8z(xrow + (size_t)px * CC + ks * 32,
                            rowok && ((unsigned)px < 128u));
        acc[t] = __builtin_amdgcn_mfma_f32_16x16x32_bf16(afrag, bfrag, acc[t], 0, 0, 0);
      }
    }
  }
  float bias = c1b[oc];
#pragma unroll
  for (int t = 0; t < 4; ++t) {
    int pxb = px0 + t * 16 + lq * 4;
    size_t base = ((size_t)b * HWPIX + (size_t)hh * WWID + pxb) * 64 + oc;
    cv1[base]       = f2b(gelu_exact(acc[t][0] + bias));
    cv1[base + 64]  = f2b(gelu_exact(acc[t][1] + bias));
    cv1[base + 128] = f2b(gelu_exact(acc[t][2] + bias));
    cv1[base + 192] = f2b(gelu_exact(acc[t][3] + bias));
  }
}

// ---- K7: conv3x3 64->192 + bias via MFMA implicit GEMM ---------------------
__global__ __launch_bounds__(256) void k_conv2m(const bf16* __restrict__ cv1,
                                                const bf16* __restrict__ wT2,
                                                const float* __restrict__ c2b,
                                                bf16* __restrict__ cv2) {
  int bi = blockIdx.x;
  int seg = bi & 1, hh = (bi >> 1) & 127, b = bi >> 8;
  int px0 = seg * 64;
  int wave = threadIdx.x >> 6, lane = threadIdx.x & 63;
  int lm = lane & 15, lq = lane >> 4;
  float4v acc[3][4];
#pragma unroll
  for (int nt = 0; nt < 3; ++nt)
#pragma unroll
    for (int t = 0; t < 4; ++t) acc[nt][t] = (float4v){0.f, 0.f, 0.f, 0.f};
#pragma unroll
  for (int tap = 0; tap < 9; ++tap) {
    int kh = tap / 3, kw = tap % 3;
    int gh = hh + kh - 1;
    bool rowok = ((unsigned)gh < 128u);
    const bf16* xrow = cv1 + ((size_t)b * HWPIX + (size_t)gh * WWID) * 64 + lq * 8;
#pragma unroll
    for (int ks = 0; ks < 2; ++ks) {
      short8 bfrag[3];
#pragma unroll
      for (int nt = 0; nt < 3; ++nt) {
        int oc = wave * 48 + nt * 16 + lm;
        bfrag[nt] = *(const short8*)(wT2 + ((size_t)tap * 192 + oc) * 64 + ks * 32 + lq * 8);
      }
#pragma unroll
      for (int t = 0; t < 4; ++t) {
        int px = px0 + t * 16 + lm + kw - 1;
        short8 afrag = ld8z(xrow + (size_t)px * 64 + ks * 32,
                            rowok && ((unsigned)px < 128u));
#pragma unroll
        for (int nt = 0; nt < 3; ++nt)
          acc[nt][t] = __builtin_amdgcn_mfma_f32_16x16x32_bf16(afrag, bfrag[nt], acc[nt][t], 0, 0, 0);
      }
    }
  }
#pragma unroll
  for (int nt = 0; nt < 3; ++nt) {
    int oc = wave * 48 + nt * 16 + lm;
    float bias = c2b[oc];
#pragma unroll
    for (int t = 0; t < 4; ++t) {
      int pxb = px0 + t * 16 + lq * 4;
      size_t base = ((size_t)b * HWPIX + (size_t)hh * WWID + pxb) * CC + oc;
      cv2[base]           = f2b(acc[nt][t][0] + bias);
      cv2[base + CC]      = f2b(acc[nt][t][1] + bias);
      cv2[base + 2 * CC]  = f2b(acc[nt][t][2] + bias);
      cv2[base + 3 * CC]  = f2b(acc[nt][t][3] + bias);
    }
  }
}

// ---------------- K8: global average pool (sum into pooled, pre-zeroed) ----
__global__ __launch_bounds__(256) void k_pool(const bf16* __restrict__ cv2,
                                              float* __restrict__ pooled) {
  __shared__ float sacc[CC];
  int t = threadIdx.x;
  if (t < CC) sacc[t] = 0.f;
  __syncthreads();
  int b = blockIdx.x >> 7;
  int pc = blockIdx.x & 127;
  const bf16* base = cv2 + (size_t)b * HWPIX * CC + (size_t)pc * 128 * CC;
  for (int it = 0; it < 96; ++it) {
    int e = it * 256 + t;
    atomicAdd(&sacc[e % CC], b2f(base[e]));
  }
  __syncthreads();
  if (t < CC) atomicAdd(&pooled[b * CC + t], sacc[t]);
}

// ---------------- K9: channel attention weights ----------------
__global__ __launch_bounds__(192) void k_ca(const float* __restrict__ pooled,
                                            const float* __restrict__ w1,
                                            const float* __restrict__ b1,
                                            const float* __restrict__ w2,
                                            const float* __restrict__ b2,
                                            float* __restrict__ ca) {
  __shared__ float pld[CC];
  __shared__ float t1[6];
  int t = threadIdx.x, b = blockIdx.x;
  pld[t] = pooled[b * CC + t] * (1.0f / HWPIX);
  __syncthreads();
  if (t < 6) {
    float s = b1[t];
    for (int c = 0; c < CC; ++c) s += pld[c] * w1[c * 6 + t];
    t1[t] = fmaxf(s, 0.f);
  }
  __syncthreads();
  float s = b2[t];
#pragma unroll
  for (int k = 0; k < 6; ++k) s += t1[k] * w2[k * CC + t];
  ca[b * CC + t] = 1.f / (1.f + __expf(-s));
}

// --- K11: fused LN2 + MLP. grid TTOT/32, block 256 (4 waves). --------------
// Phase 0 (LN2 fold): ynl = LN(y + cv2*ca*0.01) computed in-kernel into LDS
//   (time-shares the h buffer; token frags then hoisted to 48 VGPRs).
// Phase 1 (fc1+GELU): swapped-operand MFMA (A=wF1 rows -> C rows are 4
//   consecutive output channels per lane) so GELU output packs to ds_write_b64
//   into h LDS [32 tok][HSTR]. HSTR=776 shorts = 388 dw == 4 mod 32 -> rows
//   cycle all 8 bank-groups => ~2-way (free) on b128 reads and b64 writes.
// Phase 2 (fc2+residual): A=h rows from LDS, B=wF2 (L2-resident).
// __launch_bounds__(256,3): LDS caps at 3 blocks/CU anyway; this raises the
// VGPR cap to ~168 so the unrolled weight-load stream can stay in flight
// (prev build: VGPR=72 -> serialized L2 loads -> latency-bound at 204us).
__global__ __launch_bounds__(256, 3) void k_mlp(const float* __restrict__ y,
                                                const bf16* __restrict__ cv2,
                                                const float* __restrict__ ca,
                                                const float* __restrict__ g2,
                                                const float* __restrict__ bn2,
                                                const bf16* __restrict__ wF1,
                                                const bf16* __restrict__ wF2,
                                                const float* __restrict__ fb1,
                                                const float* __restrict__ fb2,
                                                float* __restrict__ out) {
  __shared__ unsigned short hl[32 * HSTR];   // 49,664 B; front 12.8 KB doubles as ynl
  unsigned short* ynl = hl;                  // [32][YSTR] bf16 LN output (dead after frag hoist)
  int tok0 = blockIdx.x * 32;
  int wave = threadIdx.x >> 6, lane = threadIdx.x & 63;
  int lm = lane & 15, lq = lane >> 4;
  const float* cab = ca + (tok0 >> 14) * CC;

  // ---- phase 0: LN2 with conv-branch fold, result -> ynl (LDS bf16) ----
  {
    float gg0 = g2[lane], gg1 = g2[lane + 64], gg2 = g2[lane + 128];
    float bb0 = bn2[lane], bb1 = bn2[lane + 64], bb2 = bn2[lane + 128];
    float c0 = cab[lane] * CONV_SC, c1 = cab[lane + 64] * CONV_SC, c2 = cab[lane + 128] * CONV_SC;
#pragma unroll
    for (int t = 0; t < 8; ++t) {
      int tl = wave * 8 + t;
      size_t row = (size_t)(tok0 + tl) * CC;
      float v0 = y[row + lane]       + b2f(cv2[row + lane])       * c0;
      float v1 = y[row + lane + 64]  + b2f(cv2[row + lane + 64])  * c1;
      float v2 = y[row + lane + 128] + b2f(cv2[row + lane + 128]) * c2;
      float s = v0 + v1 + v2, ss = v0 * v0 + v1 * v1 + v2 * v2;
#pragma unroll
      for (int off = 1; off < 64; off <<= 1) {
        s += __shfl_xor(s, off, 64);
        ss += __shfl_xor(ss, off, 64);
      }
      float mean = s * (1.0f / CC);
      float rstd = rsqrtf(ss * (1.0f / CC) - mean * mean + 1e-5f);
      ynl[tl * YSTR + lane]       = f2bu((v0 - mean) * rstd * gg0 + bb0);
      ynl[tl * YSTR + lane + 64]  = f2bu((v1 - mean) * rstd * gg1 + bb1);
      ynl[tl * YSTR + lane + 128] = f2bu((v2 - mean) * rstd * gg2 + bb2);
    }
  }
  __syncthreads();

  // hoist the 12 token B-fragments into registers (48 VGPR), freeing ynl LDS
  short8 tf[2][6];
#pragma unroll
  for (int tt = 0; tt < 2; ++tt)
#pragma unroll
    for (int ks = 0; ks < 6; ++ks)
      tf[tt][ks] = *(const short8*)&ynl[(tt * 16 + lm) * YSTR + ks * 32 + lq * 8];
  __syncthreads();   // all frag reads drained before any wave overwrites via hl

  // ---- phase 1: h = GELU(yn @ fc1 + b), swapped operands, packed b64 store -
#pragma unroll
  for (int p = 0; p < 2; ++p) {
    float4v acc[2][6];
#pragma unroll
    for (int tt = 0; tt < 2; ++tt)
#pragma unroll
      for (int nt = 0; nt < 6; ++nt) acc[tt][nt] = (float4v){0.f, 0.f, 0.f, 0.f};
#pragma unroll
    for (int ks = 0; ks < 6; ++ks) {
#pragma unroll
      for (int nt = 0; nt < 6; ++nt) {
        int n = wave * 192 + p * 96 + nt * 16 + lm;
        short8 af = *(const short8*)(wF1 + (size_t)n * CC + ks * 32 + lq * 8);
        acc[0][nt] = __builtin_amdgcn_mfma_f32_16x16x32_bf16(af, tf[0][ks], acc[0][nt], 0, 0, 0);
        acc[1][nt] = __builtin_amdgcn_mfma_f32_16x16x32_bf16(af, tf[1][ks], acc[1][nt], 0, 0, 0);
      }
    }
#pragma unroll
    for (int nt = 0; nt < 6; ++nt) {
      int n0 = wave * 192 + p * 96 + nt * 16 + lq * 4;   // 4 consecutive channels
      float4 b4 = *(const float4*)(fb1 + n0);
#pragma unroll
      for (int tt = 0; tt < 2; ++tt) {
        unsigned short u0 = f2bu(gelu_exact(acc[tt][nt][0] + b4.x));
        unsigned short u1 = f2bu(gelu_exact(acc[tt][nt][1] + b4.y));
        unsigned short u2 = f2bu(gelu_exact(acc[tt][nt][2] + b4.z));
        unsigned short u3 = f2bu(gelu_exact(acc[tt][nt][3] + b4.w));
        uint2 pk;
        pk.x = (unsigned)u0 | ((unsigned)u1 << 16);
        pk.y = (unsigned)u2 | ((unsigned)u3 << 16);
        *(uint2*)&hl[(size_t)(tt * 16 + lm) * HSTR + n0] = pk;
      }
    }
  }
  __syncthreads();

  // ---- phase 2: out = h @ fc2 + (y + cv2*ca*0.01) + b ----
  float4v acc2[2][3];
#pragma unroll
  for (int tt = 0; tt < 2; ++tt)
#pragma unroll
    for (int nt = 0; nt < 3; ++nt) acc2[tt][nt] = (float4v){0.f, 0.f, 0.f, 0.f};
#pragma unroll
  for (int ks = 0; ks < 24; ++ks) {
    short8 h0 = *(const short8*)&hl[(size_t)lm * HSTR + ks * 32 + lq * 8];
    short8 h1 = *(const short8*)&hl[(size_t)(16 + lm) * HSTR + ks * 32 + lq * 8];
#pragma unroll
    for (int nt = 0; nt < 3; ++nt) {
      int col = wave * 48 + nt * 16 + lm;
      short8 wf = *(const short8*)(wF2 + (size_t)col * 768 + ks * 32 + lq * 8);
      acc2[0][nt] = __builtin_amdgcn_mfma_f32_16x16x32_bf16(h0, wf, acc2[0][nt], 0, 0, 0);
      acc2[1][nt] = __builtin_amdgcn_mfma_f32_16x16x32_bf16(h1, wf, acc2[1][nt], 0, 0, 0);
    }
  }
#pragma unroll
  for (int tt = 0; tt < 2; ++tt)
#pragma unroll
    for (int nt = 0; nt < 3; ++nt) {
      int col = wave * 48 + nt * 16 + lm;
      float bias = fb2[col];
      float cas = cab[col] * CONV_SC;
#pragma unroll
      for (int reg = 0; reg < 4; ++reg) {
        int tok = tok0 + tt * 16 + lq * 4 + reg;
        size_t idx = (size_t)tok * CC + col;
        out[idx] = y[idx] + b2f(cv2[idx]) * cas + acc2[tt][nt][reg] + bias;
      }
    }
}

extern "C" void kernel_launch(void* const* d_in, const int* in_sizes, int n_in,
                              void* d_out, int out_size, void* d_ws, size_t ws_size,
                              hipStream_t stream) {
  const float* x      = (const float*)d_in[0];
  const float* qkv_w  = (const float*)d_in[1];
  const float* qkv_b  = (const float*)d_in[2];
  const float* proj_w = (const float*)d_in[3];
  const float* proj_b = (const float*)d_in[4];
  const float* rpb    = (const float*)d_in[5];
  const float* n1w    = (const float*)d_in[6];
  const float* n1b    = (const float*)d_in[7];
  const float* n2w    = (const float*)d_in[8];
  const float* n2b    = (const float*)d_in[9];
  const float* c1w    = (const float*)d_in[10];
  const float* c1b    = (const float*)d_in[11];
  const float* c2w    = (const float*)d_in[12];
  const float* c2b    = (const float*)d_in[13];
  const float* ca1w   = (const float*)d_in[14];
  const float* ca1b   = (const float*)d_in[15];
  const float* ca2w   = (const float*)d_in[16];
  const float* ca2b   = (const float*)d_in[17];
  const float* fc1w   = (const float*)d_in[18];
  const float* fc1b   = (const float*)d_in[19];
  const float* fc2w   = (const float*)d_in[20];
  const float* fc2b   = (const float*)d_in[21];
  const int*   rpi    = (const int*)d_in[22];
  (void)in_sizes; (void)n_in; (void)out_size; (void)ws_size;

  // ---- workspace layout: peak ~212.6 MB (< 256 MiB) ----
  char* wsb = (char*)d_ws;
  bf16*  xn    = (bf16*)(wsb + 0);            // 25,165,824
  float* biasQ = (float*)(wsb + 25165824);    //  1,572,864
  bf16*  Qg    = (bf16*)(wsb + 26738688);     // 25,165,824
  bf16*  Kg    = (bf16*)(wsb + 51904512);     // 25,165,824
  bf16*  Vg    = (bf16*)(wsb + 77070336);     // 25,165,824
  bf16*  AO    = (bf16*)(wsb + 102236160);    // 25,165,824
  float* y     = (float*)(wsb + 127401984);   // 50,331,648
  bf16*  cv1   = (bf16*)(wsb + 177733632);    //  8,388,608
  bf16*  cv2   = (bf16*)(wsb + 186122240);    // 25,165,824
  float* pool  = (float*)(wsb + 211288064);   //      3,072
  float* cavec = (float*)(wsb + 211291136);   //      3,072
  bf16*  wT1   = (bf16*)(wsb + 211294208);    //    221,184  [9][64][192]
  bf16*  wT2   = (bf16*)(wsb + 211515392);    //    221,184  [9][192][64]
  bf16*  wF1   = (bf16*)(wsb + 211736576);    //    294,912  [768][192]
  bf16*  wF2   = (bf16*)(wsb + 212031488);    //    294,912  [192][768]
  bf16*  wQv   = (bf16*)(wsb + 212326400);    //    221,184  [576][192]
  bf16*  wP    = (bf16*)(wsb + 212547584);    //     73,728  [192][192]
  float* out   = (float*)d_out;               // end 212,621,312

  k_ln1<<<TTOT / 4, 256, 0, stream>>>(x, n1w, n1b, xn);
  k_biasq<<<NHEAD * NTOK, 256, 0, stream>>>(rpi, rpb, biasQ);
  k_wprep<<<432, 256, 0, stream>>>(c1w, c2w, wT1, wT2);
  k_wprep2<<<576, 256, 0, stream>>>(fc1w, fc2w, wF1, wF2);
  k_wprep3<<<576, 256, 0, stream>>>(qkv_w, proj_w, wQv, wP);
  k_qkvg2<<<TTOT / 16, 256, 0, stream>>>(xn, wQv, qkv_b, Qg, Kg, Vg);
  k_attn2<<<BB * 64 * NHEAD * 2, 256, 0, stream>>>(Qg, Kg, Vg, biasQ, AO);
  k_proj2<<<TTOT / 16, 256, 0, stream>>>(AO, wP, proj_b, x, y);
  k_conv1m<<<1024, 256, 0, stream>>>(xn, wT1, c1b, cv1);
  k_conv2m<<<1024, 256, 0, stream>>>(cv1, wT2, c2b, cv2);
  hipMemsetAsync(pool, 0, BB * CC * sizeof(float), stream);
  k_pool<<<512, 256, 0, stream>>>(cv2, pool);
  k_ca<<<BB, 192, 0, stream>>>(pool, ca1w, ca1b, ca2w, ca2b, cavec);
  k_mlp<<<TTOT / 32, 256, 0, stream>>>(y, cv2, cavec, n2w, n2b,
                                       wF1, wF2, fc1b, fc2b, out);
}

// Round 3
// 838.761 us; speedup vs baseline: 1.2378x; 1.0510x over previous
//
#include <hip/hip_runtime.h>
#include <hip/hip_bf16.h>
#include <cstdint>
#include <cstddef>

#define BB 4
#define CC 192
#define NHEAD 6
#define WSZ 16
#define SSH 8
#define NTOK 256
#define HD 32
#define HWPIX 16384
#define TTOT 65536
#define WWID 128
#define SCALE_Q 0.17677669529663687f
#define CONV_SC 0.01f
#define PSTR 264   // attn LDS row stride (shorts): 16B-aligned, <=2-way banks
#define HSTR 776   // k_mlp h LDS row stride (shorts): 388 dw == 4 mod 32
#define YSTR 200   // k_mlp ynl row stride (shorts): 100 dw == 4 mod 32

typedef __hip_bfloat16 bf16;
typedef __attribute__((ext_vector_type(8))) short short8;
typedef __attribute__((ext_vector_type(4))) float float4v;

__device__ __forceinline__ float b2f(bf16 v) { return __bfloat162float(v); }
__device__ __forceinline__ bf16 f2b(float v) { return __float2bfloat16(v); }
__device__ __forceinline__ unsigned short f2bu(float f) {
  bf16 h = __float2bfloat16(f);
  return *reinterpret_cast<unsigned short*>(&h);
}
__device__ __forceinline__ float gelu_exact(float x) {
  return 0.5f * x * (1.0f + erff(x * 0.7071067811865475f));
}
__device__ __forceinline__ short8 ld8z(const bf16* p, bool ok) {
  if (ok) return *(const short8*)p;
  short8 z = {0, 0, 0, 0, 0, 0, 0, 0};
  return z;
}

// ---------------- K1: LayerNorm1 (x fp32 -> xn bf16). 1 wave per token -----
__global__ __launch_bounds__(256) void k_ln1(const float* __restrict__ x,
                                             const float* __restrict__ g,
                                             const float* __restrict__ b,
                                             bf16* __restrict__ xn) {
  int wv = threadIdx.x >> 6, lane = threadIdx.x & 63;
  int tok = blockIdx.x * 4 + wv;
  size_t row = (size_t)tok * CC;
  float v0 = x[row + lane], v1 = x[row + lane + 64], v2 = x[row + lane + 128];
  float s = v0 + v1 + v2, ss = v0 * v0 + v1 * v1 + v2 * v2;
#pragma unroll
  for (int off = 1; off < 64; off <<= 1) {
    s += __shfl_xor(s, off, 64);
    ss += __shfl_xor(ss, off, 64);
  }
  float mean = s * (1.0f / CC);
  float rstd = rsqrtf(ss * (1.0f / CC) - mean * mean + 1e-5f);
  xn[row + lane]       = f2b((v0 - mean) * rstd * g[lane]       + b[lane]);
  xn[row + lane + 64]  = f2b((v1 - mean) * rstd * g[lane + 64]  + b[lane + 64]);
  xn[row + lane + 128] = f2b((v2 - mean) * rstd * g[lane + 128] + b[lane + 128]);
}

// ------------- K2: bias gather biasQ[h][query][key] (fp32) ------------------
__global__ __launch_bounds__(256) void k_biasq(const int* __restrict__ rpi,
                                               const float* __restrict__ rpb,
                                               float* __restrict__ biasQ) {
  int k = threadIdx.x;
  int h = blockIdx.x >> 8;
  int q = blockIdx.x & 255;
  biasQ[(size_t)blockIdx.x * 256 + k] = rpb[rpi[q * 256 + k] * NHEAD + h];
}

// ------- K2b: conv weight transpose to [tap][oc][ci] bf16 -------------------
__global__ __launch_bounds__(256) void k_wprep(const float* __restrict__ c1w,
                                               const float* __restrict__ c2w,
                                               bf16* __restrict__ wT1,
                                               bf16* __restrict__ wT2) {
  int i = blockIdx.x * 256 + threadIdx.x;   // 0 .. 110591
  {
    int tap = i / (64 * 192); int r = i % (64 * 192);
    int oc = r / 192, ci = r % 192;
    wT1[i] = f2b(c1w[(size_t)(tap * 192 + ci) * 64 + oc]);
  }
  {
    int tap = i / (192 * 64); int r = i % (192 * 64);
    int oc = r / 64, ci = r % 64;
    wT2[i] = f2b(c2w[(size_t)(tap * 64 + ci) * 192 + oc]);
  }
}

// ------- K2c: MLP weight transpose to n-major bf16 --------------------------
__global__ __launch_bounds__(256) void k_wprep2(const float* __restrict__ fc1w,
                                                const float* __restrict__ fc2w,
                                                bf16* __restrict__ wF1,
                                                bf16* __restrict__ wF2) {
  int i = blockIdx.x * 256 + threadIdx.x;   // 0 .. 147455
  {
    int n = i / 192, k = i % 192;           // wF1[n][k], n<768 k<192
    wF1[i] = f2b(fc1w[(size_t)k * 768 + n]);
  }
  {
    int n = i / 768, k = i % 768;           // wF2[n][k], n<192 k<768
    wF2[i] = f2b(fc2w[(size_t)k * 192 + n]);
  }
}

// ------- K2d: qkv/proj weight transpose to n-major bf16 ---------------------
__global__ __launch_bounds__(256) void k_wprep3(const float* __restrict__ qkvw,
                                                const float* __restrict__ projw,
                                                bf16* __restrict__ wQv,
                                                bf16* __restrict__ wP) {
  int i = blockIdx.x * 256 + threadIdx.x;   // 0 .. 147455 (grid 576)
  if (i < 576 * 192) {
    int n = i / 192, k = i % 192;           // wQv[n][k], n<576
    wQv[i] = f2b(qkvw[(size_t)k * 576 + n]);
  }
  if (i < 192 * 192) {
    int n = i / 192, k = i % 192;           // wP[n][k]
    wP[i] = f2b(projw[(size_t)k * 192 + n]);
  }
}

// --- K3: QKV GEMM via MFMA (N=576, K=192), gathered scatter store -----------
// grid TTOT/32, block 256 (4 waves). Wave w: cols w*144..+143 (9 tiles).
// 2 token-tiles per block: each weight fragment feeds 2 MFMA (was 1) and
// wQv L2 traffic per token halves.
__global__ __launch_bounds__(256) void k_qkvg2(const bf16* __restrict__ xn,
                                               const bf16* __restrict__ wQv,
                                               const float* __restrict__ qb,
                                               bf16* __restrict__ Qg,
                                               bf16* __restrict__ Kg,
                                               bf16* __restrict__ Vg) {
  int tok0 = blockIdx.x * 32;
  int wave = threadIdx.x >> 6, lane = threadIdx.x & 63;
  int lm = lane & 15, lq = lane >> 4;
  const bf16* arow0 = xn + (size_t)(tok0 + lm) * CC + lq * 8;
  const bf16* arow1 = xn + (size_t)(tok0 + 16 + lm) * CC + lq * 8;
  float4v acc[9][2];
#pragma unroll
  for (int nt = 0; nt < 9; ++nt)
#pragma unroll
    for (int tt = 0; tt < 2; ++tt) acc[nt][tt] = (float4v){0.f, 0.f, 0.f, 0.f};
#pragma unroll
  for (int ks = 0; ks < 6; ++ks) {
    short8 af0 = *(const short8*)(arow0 + ks * 32);
    short8 af1 = *(const short8*)(arow1 + ks * 32);
#pragma unroll
    for (int nt = 0; nt < 9; ++nt) {
      int col = wave * 144 + nt * 16 + lm;
      short8 bfrag = *(const short8*)(wQv + (size_t)col * CC + ks * 32 + lq * 8);
      acc[nt][0] = __builtin_amdgcn_mfma_f32_16x16x32_bf16(af0, bfrag, acc[nt][0], 0, 0, 0);
      acc[nt][1] = __builtin_amdgcn_mfma_f32_16x16x32_bf16(af1, bfrag, acc[nt][1], 0, 0, 0);
    }
  }
  // per-(tt,reg) token -> gathered (window,head) coords
  size_t base[2][4];
#pragma unroll
  for (int tt = 0; tt < 2; ++tt)
#pragma unroll
    for (int reg = 0; reg < 4; ++reg) {
      int tg = tok0 + tt * 16 + lq * 4 + reg;
      int b = tg >> 14;
      int pix = tg & 16383;
      int gh = pix >> 7, gw = pix & 127;
      int hs = (gh + 120) & 127, wsx = (gw + 120) & 127;
      int wdx = (b << 6) + ((hs >> 4) << 3) + (wsx >> 4);
      int ndx = ((hs & 15) << 4) + (wsx & 15);
      base[tt][reg] = ((size_t)wdx * NHEAD) * NTOK * HD + (size_t)ndx * HD;
    }
#pragma unroll
  for (int nt = 0; nt < 9; ++nt) {
    int col = wave * 144 + nt * 16 + lm;
    float bias = qb[col];
    int sect = col / 192, within = col - sect * 192;
    int head = within >> 5, d = within & 31;
    bf16* dst = (sect == 0) ? Qg : (sect == 1) ? Kg : Vg;
    float scale = (sect == 0) ? SCALE_Q : 1.f;
#pragma unroll
    for (int tt = 0; tt < 2; ++tt)
#pragma unroll
      for (int reg = 0; reg < 4; ++reg) {
        dst[base[tt][reg] + (size_t)head * NTOK * HD + d] =
            f2b((acc[nt][tt][reg] + bias) * scale);
      }
  }
}

// --- K4: windowed attention via MFMA --------------------------------------
// grid = 1536*2 (wh, query-half). block 256 = 4 waves x 32 queries.
// S = Q*K^T (MFMA), full softmax per 16-row tile, P->LDS bf16, O = P*V (MFMA).
__global__ __launch_bounds__(256) void k_attn2(const bf16* __restrict__ Qg,
                                               const bf16* __restrict__ Kg,
                                               const bf16* __restrict__ Vg,
                                               const float* __restrict__ biasQ,
                                               bf16* __restrict__ AO) {
  __shared__ unsigned short PTw[4][16 * PSTR];  // 33,792 B (wave-private P tiles)
  __shared__ unsigned short VT[32 * PSTR];      // 16,896 B (V transposed)
  int wh = blockIdx.x >> 1, half = blockIdx.x & 1;
  int wdx = wh / NHEAD, h = wh - wdx * NHEAD;
  int wl = wdx & 63;
  int wr = wl >> 3, wc = wl & 7;
  int tid = threadIdx.x;
  int wave = tid >> 6, lane = tid & 63;
  int lm = lane & 15, lq = lane >> 4;
  int q0 = half * 128;

  // stage V^T: thread tid handles key row tid
  {
    const uint4* vp = (const uint4*)(Vg + ((size_t)wh * NTOK + tid) * HD);
    uint4 vv[4] = {vp[0], vp[1], vp[2], vp[3]};
#pragma unroll
    for (int i = 0; i < 4; ++i) {
      unsigned arr[4] = {vv[i].x, vv[i].y, vv[i].z, vv[i].w};
#pragma unroll
      for (int j = 0; j < 4; ++j) {
        int d = i * 8 + j * 2;
        VT[d * PSTR + tid]       = (unsigned short)(arr[j] & 0xffffu);
        VT[(d + 1) * PSTR + tid] = (unsigned short)(arr[j] >> 16);
      }
    }
  }
  __syncthreads();

  int wsk = (wc << 4) + lm;                       // lane's key col (w coord)
  int ridk_w = (wsk >= 112) + (wsk >= 120);
  unsigned short* PT = &PTw[wave][0];

  float4v oacc[2][2];
#pragma unroll
  for (int rt = 0; rt < 2; ++rt)
#pragma unroll
    for (int c2 = 0; c2 < 2; ++c2) oacc[rt][c2] = (float4v){0.f, 0.f, 0.f, 0.f};
  float linv[2][4];

#pragma unroll
  for (int rt = 0; rt < 2; ++rt) {
    int qrow = q0 + wave * 32 + rt * 16;
    short8 aq = *(const short8*)(Qg + ((size_t)wh * NTOK + qrow + lm) * HD + lq * 8);
    float4v sacc[16];
#pragma unroll
    for (int ct = 0; ct < 16; ++ct) sacc[ct] = (float4v){0.f, 0.f, 0.f, 0.f};
#pragma unroll
    for (int ct = 0; ct < 16; ++ct) {
      short8 kf = *(const short8*)(Kg + ((size_t)wh * NTOK + ct * 16 + lm) * HD + lq * 8);
      sacc[ct] = __builtin_amdgcn_mfma_f32_16x16x32_bf16(aq, kf, sacc[ct], 0, 0, 0);
    }
    // softmax over 256 keys, rows lq*4+reg of this 16-row tile
#pragma unroll
    for (int reg = 0; reg < 4; ++reg) {
      int nq = qrow + lq * 4 + reg;
      int hsq = (wr << 4) + (nq >> 4), wsq = (wc << 4) + (nq & 15);
      int ridq = ((hsq >= 112) + (hsq >= 120)) * 3 + ((wsq >= 112) + (wsq >= 120));
      const float* bq = biasQ + ((size_t)(h * 256 + nq)) * 256 + lm;
      float sv[16];
      float mx = -1.0e30f;
#pragma unroll
      for (int ct = 0; ct < 16; ++ct) {
        int hsk = (wr << 4) + ct;
        int ridk = ((hsk >= 112) + (hsk >= 120)) * 3 + ridk_w;
        float s = sacc[ct][reg] + bq[ct * 16] + ((ridk != ridq) ? -100.f : 0.f);
        sv[ct] = s;
        mx = fmaxf(mx, s);
      }
#pragma unroll
      for (int off = 1; off < 16; off <<= 1) mx = fmaxf(mx, __shfl_xor(mx, off, 64));
      float l = 0.f;
#pragma unroll
      for (int ct = 0; ct < 16; ++ct) {
        float p = __expf(sv[ct] - mx);
        l += p;
        PT[(lq * 4 + reg) * PSTR + ct * 16 + lm] = f2bu(p);
      }
#pragma unroll
      for (int off = 1; off < 16; off <<= 1) l += __shfl_xor(l, off, 64);
      linv[rt][reg] = 1.f / l;
    }
    // PV for this row tile: A = P rows (wave-private, in-wave LDS ordering)
#pragma unroll
    for (int kb = 0; kb < 8; ++kb) {
      short8 pf = *(const short8*)&PT[lm * PSTR + kb * 32 + lq * 8];
#pragma unroll
      for (int c2 = 0; c2 < 2; ++c2) {
        short8 vf = *(const short8*)&VT[(c2 * 16 + lm) * PSTR + kb * 32 + lq * 8];
        oacc[rt][c2] = __builtin_amdgcn_mfma_f32_16x16x32_bf16(pf, vf, oacc[rt][c2], 0, 0, 0);
      }
    }
  }
  // write AO
#pragma unroll
  for (int rt = 0; rt < 2; ++rt)
#pragma unroll
    for (int c2 = 0; c2 < 2; ++c2) {
      int d = c2 * 16 + lm;
#pragma unroll
      for (int reg = 0; reg < 4; ++reg) {
        int nq = q0 + wave * 32 + rt * 16 + lq * 4 + reg;
        AO[((size_t)wdx * NTOK + nq) * CC + h * HD + d] =
            f2b(oacc[rt][c2][reg] * linv[rt][reg]);
      }
    }
}

// --- K5: proj GEMM via MFMA (N=192, K=192) + shift-reverse + x residual -----
// grid TTOT/32 (win-order rows), block 256 (4 waves). Wave w: cols w*48..+47.
// 2 token-tiles per block: each wP fragment feeds 2 MFMA.
__global__ __launch_bounds__(256) void k_proj2(const bf16* __restrict__ AO,
                                               const bf16* __restrict__ wP,
                                               const float* __restrict__ pb,
                                               const float* __restrict__ x,
                                               float* __restrict__ y) {
  int r0 = blockIdx.x * 32;
  int wave = threadIdx.x >> 6, lane = threadIdx.x & 63;
  int lm = lane & 15, lq = lane >> 4;
  const bf16* arow0 = AO + (size_t)(r0 + lm) * CC + lq * 8;
  const bf16* arow1 = AO + (size_t)(r0 + 16 + lm) * CC + lq * 8;
  float4v acc[3][2];
#pragma unroll
  for (int nt = 0; nt < 3; ++nt)
#pragma unroll
    for (int tt = 0; tt < 2; ++tt) acc[nt][tt] = (float4v){0.f, 0.f, 0.f, 0.f};
#pragma unroll
  for (int ks = 0; ks < 6; ++ks) {
    short8 af0 = *(const short8*)(arow0 + ks * 32);
    short8 af1 = *(const short8*)(arow1 + ks * 32);
#pragma unroll
    for (int nt = 0; nt < 3; ++nt) {
      int col = wave * 48 + nt * 16 + lm;
      short8 bfrag = *(const short8*)(wP + (size_t)col * CC + ks * 32 + lq * 8);
      acc[nt][0] = __builtin_amdgcn_mfma_f32_16x16x32_bf16(af0, bfrag, acc[nt][0], 0, 0, 0);
      acc[nt][1] = __builtin_amdgcn_mfma_f32_16x16x32_bf16(af1, bfrag, acc[nt][1], 0, 0, 0);
    }
  }
  size_t drow[2][4];
#pragma unroll
  for (int tt = 0; tt < 2; ++tt)
#pragma unroll
    for (int reg = 0; reg < 4; ++reg) {
      int r = r0 + tt * 16 + lq * 4 + reg;
      int wdx = r >> 8, n = r & 255;
      int wb = wdx >> 6, wl = wdx & 63;
      int hs = ((wl >> 3) << 4) + (n >> 4);
      int wsx = ((wl & 7) << 4) + (n & 15);
      int gh = (hs + SSH) & 127, gw = (wsx + SSH) & 127;
      drow[tt][reg] = ((size_t)wb * HWPIX + (size_t)gh * WWID + gw) * CC;
    }
#pragma unroll
  for (int nt = 0; nt < 3; ++nt) {
    int col = wave * 48 + nt * 16 + lm;
    float bias = pb[col];
#pragma unroll
    for (int tt = 0; tt < 2; ++tt)
#pragma unroll
      for (int reg = 0; reg < 4; ++reg) {
        y[drow[tt][reg] + col] = x[drow[tt][reg] + col] + acc[nt][tt][reg] + bias;
      }
  }
}

// ---- K6: conv3x3 192->64 + GELU via MFMA implicit GEMM ---------------------
__global__ __launch_bounds__(256) void k_conv1m(const bf16* __restrict__ xn,
                                                const bf16* __restrict__ wT1,
                                                const float* __restrict__ c1b,
                                                bf16* __restrict__ cv1) {
  int bi = blockIdx.x;
  int seg = bi & 1, hh = (bi >> 1) & 127, b = bi >> 8;
  int px0 = seg * 64;
  int wave = threadIdx.x >> 6, lane = threadIdx.x & 63;
  int lm = lane & 15, lq = lane >> 4;
  int oc = wave * 16 + lm;
  float4v acc[4];
#pragma unroll
  for (int t = 0; t < 4; ++t) acc[t] = (float4v){0.f, 0.f, 0.f, 0.f};
#pragma unroll
  for (int tap = 0; tap < 9; ++tap) {
    int kh = tap / 3, kw = tap % 3;
    int gh = hh + kh - 1;
    bool rowok = ((unsigned)gh < 128u);
    const bf16* wrow = wT1 + ((size_t)tap * 64 + oc) * CC + lq * 8;
    const bf16* xrow = xn + ((size_t)b * HWPIX + (size_t)gh * WWID) * CC + lq * 8;
#pragma unroll
    for (int ks = 0; ks < 6; ++ks) {
      short8 bfrag = *(const short8*)(wrow + ks * 32);
#pragma unroll
      for (int t = 0; t < 4; ++t) {
        int px = px0 + t * 16 + lm + kw - 1;
        short8 afrag = ld8z(xrow + (size_t)px * CC + ks * 32,
                            rowok && ((unsigned)px < 128u));
        acc[t] = __builtin_amdgcn_mfma_f32_16x16x32_bf16(afrag, bfrag, acc[t], 0, 0, 0);
      }
    }
  }
  float bias = c1b[oc];
#pragma unroll
  for (int t = 0; t < 4; ++t) {
    int pxb = px0 + t * 16 + lq * 4;
    size_t base = ((size_t)b * HWPIX + (size_t)hh * WWID + pxb) * 64 + oc;
    cv1[base]       = f2b(gelu_exact(acc[t][0] + bias));
    cv1[base + 64]  = f2b(gelu_exact(acc[t][1] + bias));
    cv1[base + 128] = f2b(gelu_exact(acc[t][2] + bias));
    cv1[base + 192] = f2b(gelu_exact(acc[t][3] + bias));
  }
}

// ---- K7: conv3x3 64->192 + bias via MFMA implicit GEMM ---------------------
__global__ __launch_bounds__(256) void k_conv2m(const bf16* __restrict__ cv1,
                                                const bf16* __restrict__ wT2,
                                                const float* __restrict__ c2b,
                                                bf16* __restrict__ cv2) {
  int bi = blockIdx.x;
  int seg = bi & 1, hh = (bi >> 1) & 127, b = bi >> 8;
  int px0 = seg * 64;
  int wave = threadIdx.x >> 6, lane = threadIdx.x & 63;
  int lm = lane & 15, lq = lane >> 4;
  float4v acc[3][4];
#pragma unroll
  for (int nt = 0; nt < 3; ++nt)
#pragma unroll
    for (int t = 0; t < 4; ++t) acc[nt][t] = (float4v){0.f, 0.f, 0.f, 0.f};
#pragma unroll
  for (int tap = 0; tap < 9; ++tap) {
    int kh = tap / 3, kw = tap % 3;
    int gh = hh + kh - 1;
    bool rowok = ((unsigned)gh < 128u);
    const bf16* xrow = cv1 + ((size_t)b * HWPIX + (size_t)gh * WWID) * 64 + lq * 8;
#pragma unroll
    for (int ks = 0; ks < 2; ++ks) {
      short8 bfrag[3];
#pragma unroll
      for (int nt = 0; nt < 3; ++nt) {
        int oc = wave * 48 + nt * 16 + lm;
        bfrag[nt] = *(const short8*)(wT2 + ((size_t)tap * 192 + oc) * 64 + ks * 32 + lq * 8);
      }
#pragma unroll
      for (int t = 0; t < 4; ++t) {
        int px = px0 + t * 16 + lm + kw - 1;
        short8 afrag = ld8z(xrow + (size_t)px * 64 + ks * 32,
                            rowok && ((unsigned)px < 128u));
#pragma unroll
        for (int nt = 0; nt < 3; ++nt)
          acc[nt][t] = __builtin_amdgcn_mfma_f32_16x16x32_bf16(afrag, bfrag[nt], acc[nt][t], 0, 0, 0);
      }
    }
  }
#pragma unroll
  for (int nt = 0; nt < 3; ++nt) {
    int oc = wave * 48 + nt * 16 + lm;
    float bias = c2b[oc];
#pragma unroll
    for (int t = 0; t < 4; ++t) {
      int pxb = px0 + t * 16 + lq * 4;
      size_t base = ((size_t)b * HWPIX + (size_t)hh * WWID + pxb) * CC + oc;
      cv2[base]           = f2b(acc[nt][t][0] + bias);
      cv2[base + CC]      = f2b(acc[nt][t][1] + bias);
      cv2[base + 2 * CC]  = f2b(acc[nt][t][2] + bias);
      cv2[base + 3 * CC]  = f2b(acc[nt][t][3] + bias);
    }
  }
}

// ---------------- K8: global average pool (sum into pooled, pre-zeroed) ----
// thread t owns channel t; register accumulation over 128 pixels (coalesced
// 128B rows per wave), one global atomic per thread. Replaces 12.6M LDS
// atomics of the previous version.
__global__ __launch_bounds__(192) void k_pool(const bf16* __restrict__ cv2,
                                              float* __restrict__ pooled) {
  int t = threadIdx.x;                        // channel
  int b = blockIdx.x >> 7;
  int pc = blockIdx.x & 127;                  // 128-pixel chunk
  const bf16* base = cv2 + ((size_t)b * HWPIX + (size_t)pc * 128) * CC + t;
  float s = 0.f;
#pragma unroll 4
  for (int p = 0; p < 128; ++p) s += b2f(base[(size_t)p * CC]);
  atomicAdd(&pooled[b * CC + t], s);
}

// ---------------- K9: channel attention weights ----------------
__global__ __launch_bounds__(192) void k_ca(const float* __restrict__ pooled,
                                            const float* __restrict__ w1,
                                            const float* __restrict__ b1,
                                            const float* __restrict__ w2,
                                            const float* __restrict__ b2,
                                            float* __restrict__ ca) {
  __shared__ float pld[CC];
  __shared__ float t1[6];
  int t = threadIdx.x, b = blockIdx.x;
  pld[t] = pooled[b * CC + t] * (1.0f / HWPIX);
  __syncthreads();
  if (t < 6) {
    float s = b1[t];
    for (int c = 0; c < CC; ++c) s += pld[c] * w1[c * 6 + t];
    t1[t] = fmaxf(s, 0.f);
  }
  __syncthreads();
  float s = b2[t];
#pragma unroll
  for (int k = 0; k < 6; ++k) s += t1[k] * w2[k * CC + t];
  ca[b * CC + t] = 1.f / (1.f + __expf(-s));
}

// --- K11: fused LN2 + MLP. grid TTOT/64, block 512 (8 waves), 64 tokens. ---
// Phase 0: ynl = LN(y + cv2*ca*0.01) -> separate LDS buffer (25.6 KB, kept
//   alive through phase 1 so token fragments are re-read per ks -- keeps
//   VGPR pressure low while each weight fragment feeds 4 MFMA).
// Phase 1: wave w owns cols [w*96,(w+1)*96), p-split into 2x48. Per weight
//   fragment: 4 token-tiles -> 4 MFMA/load (was 2), wF1 traffic/token halved.
// Phase 2: wave = (token-half tth, col-quarter colg): 2 tt x 48 cols, k=768.
//   Waves tth=0/1 with same colg read identical wF2 rows -> 2-way L1 share.
// LDS total 124,928 B -> 1 block/CU, 8 waves = 2/SIMD, VGPR cap 256.
__global__ __launch_bounds__(512, 2) void k_mlp(const float* __restrict__ y,
                                                const bf16* __restrict__ cv2,
                                                const float* __restrict__ ca,
                                                const float* __restrict__ g2,
                                                const float* __restrict__ bn2,
                                                const bf16* __restrict__ wF1,
                                                const bf16* __restrict__ wF2,
                                                const float* __restrict__ fb1,
                                                const float* __restrict__ fb2,
                                                float* __restrict__ out) {
  __shared__ unsigned short hl[64 * HSTR];    // 99,328 B
  __shared__ unsigned short ynl[64 * YSTR];   // 25,600 B
  int tok0 = blockIdx.x * 64;
  int wave = threadIdx.x >> 6, lane = threadIdx.x & 63;
  int lm = lane & 15, lq = lane >> 4;
  const float* cab = ca + (tok0 >> 14) * CC;

  // ---- phase 0: LN2 with conv-branch fold, result -> ynl (LDS bf16) ----
  {
    float gg0 = g2[lane], gg1 = g2[lane + 64], gg2 = g2[lane + 128];
    float bb0 = bn2[lane], bb1 = bn2[lane + 64], bb2 = bn2[lane + 128];
    float c0 = cab[lane] * CONV_SC, c1 = cab[lane + 64] * CONV_SC, c2 = cab[lane + 128] * CONV_SC;
#pragma unroll
    for (int t = 0; t < 8; ++t) {
      int tl = wave * 8 + t;
      size_t row = (size_t)(tok0 + tl) * CC;
      float v0 = y[row + lane]       + b2f(cv2[row + lane])       * c0;
      float v1 = y[row + lane + 64]  + b2f(cv2[row + lane + 64])  * c1;
      float v2 = y[row + lane + 128] + b2f(cv2[row + lane + 128]) * c2;
      float s = v0 + v1 + v2, ss = v0 * v0 + v1 * v1 + v2 * v2;
#pragma unroll
      for (int off = 1; off < 64; off <<= 1) {
        s += __shfl_xor(s, off, 64);
        ss += __shfl_xor(ss, off, 64);
      }
      float mean = s * (1.0f / CC);
      float rstd = rsqrtf(ss * (1.0f / CC) - mean * mean + 1e-5f);
      ynl[tl * YSTR + lane]       = f2bu((v0 - mean) * rstd * gg0 + bb0);
      ynl[tl * YSTR + lane + 64]  = f2bu((v1 - mean) * rstd * gg1 + bb1);
      ynl[tl * YSTR + lane + 128] = f2bu((v2 - mean) * rstd * gg2 + bb2);
    }
  }
  __syncthreads();

  // ---- phase 1: h = GELU(yn @ fc1 + b), 4 token-tiles per weight load ----
#pragma unroll
  for (int p = 0; p < 2; ++p) {
    float4v acc[4][3];
#pragma unroll
    for (int tt = 0; tt < 4; ++tt)
#pragma unroll
      for (int nt = 0; nt < 3; ++nt) acc[tt][nt] = (float4v){0.f, 0.f, 0.f, 0.f};
#pragma unroll
    for (int ks = 0; ks < 6; ++ks) {
      short8 tfk[4];
#pragma unroll
      for (int tt = 0; tt < 4; ++tt)
        tfk[tt] = *(const short8*)&ynl[(tt * 16 + lm) * YSTR + ks * 32 + lq * 8];
#pragma unroll
      for (int nt = 0; nt < 3; ++nt) {
        int n = wave * 96 + p * 48 + nt * 16 + lm;
        short8 af = *(const short8*)(wF1 + (size_t)n * CC + ks * 32 + lq * 8);
#pragma unroll
        for (int tt = 0; tt < 4; ++tt)
          acc[tt][nt] = __builtin_amdgcn_mfma_f32_16x16x32_bf16(af, tfk[tt], acc[tt][nt], 0, 0, 0);
      }
    }
#pragma unroll
    for (int nt = 0; nt < 3; ++nt) {
      int n0 = wave * 96 + p * 48 + nt * 16 + lq * 4;   // 4 consecutive channels
      float4 b4 = *(const float4*)(fb1 + n0);
#pragma unroll
      for (int tt = 0; tt < 4; ++tt) {
        unsigned short u0 = f2bu(gelu_exact(acc[tt][nt][0] + b4.x));
        unsigned short u1 = f2bu(gelu_exact(acc[tt][nt][1] + b4.y));
        unsigned short u2 = f2bu(gelu_exact(acc[tt][nt][2] + b4.z));
        unsigned short u3 = f2bu(gelu_exact(acc[tt][nt][3] + b4.w));
        uint2 pk;
        pk.x = (unsigned)u0 | ((unsigned)u1 << 16);
        pk.y = (unsigned)u2 | ((unsigned)u3 << 16);
        *(uint2*)&hl[(size_t)(tt * 16 + lm) * HSTR + n0] = pk;
      }
    }
  }
  __syncthreads();

  // ---- phase 2: out = h @ fc2 + (y + cv2*ca*0.01) + b ----
  int tth = wave >> 2, colg = wave & 3;
  float4v acc2[2][3];
#pragma unroll
  for (int tt = 0; tt < 2; ++tt)
#pragma unroll
    for (int nt = 0; nt < 3; ++nt) acc2[tt][nt] = (float4v){0.f, 0.f, 0.f, 0.f};
#pragma unroll
  for (int ks = 0; ks < 24; ++ks) {
    short8 h0 = *(const short8*)&hl[(size_t)((tth * 2 + 0) * 16 + lm) * HSTR + ks * 32 + lq * 8];
    short8 h1 = *(const short8*)&hl[(size_t)((tth * 2 + 1) * 16 + lm) * HSTR + ks * 32 + lq * 8];
#pragma unroll
    for (int nt = 0; nt < 3; ++nt) {
      int col = colg * 48 + nt * 16 + lm;
      short8 wf = *(const short8*)(wF2 + (size_t)col * 768 + ks * 32 + lq * 8);
      acc2[0][nt] = __builtin_amdgcn_mfma_f32_16x16x32_bf16(h0, wf, acc2[0][nt], 0, 0, 0);
      acc2[1][nt] = __builtin_amdgcn_mfma_f32_16x16x32_bf16(h1, wf, acc2[1][nt], 0, 0, 0);
    }
  }
#pragma unroll
  for (int tt = 0; tt < 2; ++tt)
#pragma unroll
    for (int nt = 0; nt < 3; ++nt) {
      int col = colg * 48 + nt * 16 + lm;
      float bias = fb2[col];
      float cas = cab[col] * CONV_SC;
#pragma unroll
      for (int reg = 0; reg < 4; ++reg) {
        int tok = tok0 + (tth * 2 + tt) * 16 + lq * 4 + reg;
        size_t idx = (size_t)tok * CC + col;
        out[idx] = y[idx] + b2f(cv2[idx]) * cas + acc2[tt][nt][reg] + bias;
      }
    }
}

extern "C" void kernel_launch(void* const* d_in, const int* in_sizes, int n_in,
                              void* d_out, int out_size, void* d_ws, size_t ws_size,
                              hipStream_t stream) {
  const float* x      = (const float*)d_in[0];
  const float* qkv_w  = (const float*)d_in[1];
  const float* qkv_b  = (const float*)d_in[2];
  const float* proj_w = (const float*)d_in[3];
  const float* proj_b = (const float*)d_in[4];
  const float* rpb    = (const float*)d_in[5];
  const float* n1w    = (const float*)d_in[6];
  const float* n1b    = (const float*)d_in[7];
  const float* n2w    = (const float*)d_in[8];
  const float* n2b    = (const float*)d_in[9];
  const float* c1w    = (const float*)d_in[10];
  const float* c1b    = (const float*)d_in[11];
  const float* c2w    = (const float*)d_in[12];
  const float* c2b    = (const float*)d_in[13];
  const float* ca1w   = (const float*)d_in[14];
  const float* ca1b   = (const float*)d_in[15];
  const float* ca2w   = (const float*)d_in[16];
  const float* ca2b   = (const float*)d_in[17];
  const float* fc1w   = (const float*)d_in[18];
  const float* fc1b   = (const float*)d_in[19];
  const float* fc2w   = (const float*)d_in[20];
  const float* fc2b   = (const float*)d_in[21];
  const int*   rpi    = (const int*)d_in[22];
  (void)in_sizes; (void)n_in; (void)out_size; (void)ws_size;

  // ---- workspace layout: peak ~212.6 MB (< 256 MiB) ----
  char* wsb = (char*)d_ws;
  bf16*  xn    = (bf16*)(wsb + 0);            // 25,165,824
  float* biasQ = (float*)(wsb + 25165824);    //  1,572,864
  bf16*  Qg    = (bf16*)(wsb + 26738688);     // 25,165,824
  bf16*  Kg    = (bf16*)(wsb + 51904512);     // 25,165,824
  bf16*  Vg    = (bf16*)(wsb + 77070336);     // 25,165,824
  bf16*  AO    = (bf16*)(wsb + 102236160);    // 25,165,824
  float* y     = (float*)(wsb + 127401984);   // 50,331,648
  bf16*  cv1   = (bf16*)(wsb + 177733632);    //  8,388,608
  bf16*  cv2   = (bf16*)(wsb + 186122240);    // 25,165,824
  float* pool  = (float*)(wsb + 211288064);   //      3,072
  float* cavec = (float*)(wsb + 211291136);   //      3,072
  bf16*  wT1   = (bf16*)(wsb + 211294208);    //    221,184  [9][64][192]
  bf16*  wT2   = (bf16*)(wsb + 211515392);    //    221,184  [9][192][64]
  bf16*  wF1   = (bf16*)(wsb + 211736576);    //    294,912  [768][192]
  bf16*  wF2   = (bf16*)(wsb + 212031488);    //    294,912  [192][768]
  bf16*  wQv   = (bf16*)(wsb + 212326400);    //    221,184  [576][192]
  bf16*  wP    = (bf16*)(wsb + 212547584);    //     73,728  [192][192]
  float* out   = (float*)d_out;               // end 212,621,312

  k_ln1<<<TTOT / 4, 256, 0, stream>>>(x, n1w, n1b, xn);
  k_biasq<<<NHEAD * NTOK, 256, 0, stream>>>(rpi, rpb, biasQ);
  k_wprep<<<432, 256, 0, stream>>>(c1w, c2w, wT1, wT2);
  k_wprep2<<<576, 256, 0, stream>>>(fc1w, fc2w, wF1, wF2);
  k_wprep3<<<576, 256, 0, stream>>>(qkv_w, proj_w, wQv, wP);
  k_qkvg2<<<TTOT / 32, 256, 0, stream>>>(xn, wQv, qkv_b, Qg, Kg, Vg);
  k_attn2<<<BB * 64 * NHEAD * 2, 256, 0, stream>>>(Qg, Kg, Vg, biasQ, AO);
  k_proj2<<<TTOT / 32, 256, 0, stream>>>(AO, wP, proj_b, x, y);
  k_conv1m<<<1024, 256, 0, stream>>>(xn, wT1, c1b, cv1);
  k_conv2m<<<1024, 256, 0, stream>>>(cv1, wT2, c2b, cv2);
  hipMemsetAsync(pool, 0, BB * CC * sizeof(float), stream);
  k_pool<<<512, 192, 0, stream>>>(cv2, pool);
  k_ca<<<BB, 192, 0, stream>>>(pool, ca1w, ca1b, ca2w, ca2b, cavec);
  k_mlp<<<TTOT / 64, 512, 0, stream>>>(y, cv2, cavec, n2w, n2b,
                                       wF1, wF2, fc1b, fc2b, out);
}

// Round 4
// 820.124 us; speedup vs baseline: 1.2659x; 1.0227x over previous
//
#include <hip/hip_runtime.h>
#include <hip/hip_bf16.h>
#include <cstdint>
#include <cstddef>

#define BB 4
#define CC 192
#define NHEAD 6
#define WSZ 16
#define SSH 8
#define NTOK 256
#define HD 32
#define HWPIX 16384
#define TTOT 65536
#define WWID 128
#define SCALE_Q 0.17677669529663687f
#define CONV_SC 0.01f
#define PSTR 264   // attn LDS row stride (shorts): 16B-aligned, <=2-way banks
#define HSTR 776   // k_mlp h LDS row stride (shorts): 388 dw == 4 mod 32
#define YSTR 200   // k_mlp ynl row stride (shorts): 100 dw == 4 mod 32

typedef __hip_bfloat16 bf16;
typedef __attribute__((ext_vector_type(8))) short short8;
typedef __attribute__((ext_vector_type(4))) float float4v;

__device__ __forceinline__ float b2f(bf16 v) { return __bfloat162float(v); }
__device__ __forceinline__ bf16 f2b(float v) { return __float2bfloat16(v); }
__device__ __forceinline__ unsigned short f2bu(float f) {
  bf16 h = __float2bfloat16(f);
  return *reinterpret_cast<unsigned short*>(&h);
}
__device__ __forceinline__ float gelu_exact(float x) {
  return 0.5f * x * (1.0f + erff(x * 0.7071067811865475f));
}
__device__ __forceinline__ short8 ld8z(const bf16* p, bool ok) {
  if (ok) return *(const short8*)p;
  short8 z = {0, 0, 0, 0, 0, 0, 0, 0};
  return z;
}
// async global->LDS 16B per lane: LDS dest = wave-uniform base + lane*16,
// global source is per-lane (m173). size must be literal 16.
__device__ __forceinline__ void glds16(const void* g, void* l) {
  __builtin_amdgcn_global_load_lds(
      (const __attribute__((address_space(1))) unsigned int*)g,
      (__attribute__((address_space(3))) unsigned int*)l, 16, 0, 0);
}

// ---------------- K1: LayerNorm1 (x fp32 -> xn bf16). 1 wave per token -----
__global__ __launch_bounds__(256) void k_ln1(const float* __restrict__ x,
                                             const float* __restrict__ g,
                                             const float* __restrict__ b,
                                             bf16* __restrict__ xn) {
  int wv = threadIdx.x >> 6, lane = threadIdx.x & 63;
  int tok = blockIdx.x * 4 + wv;
  size_t row = (size_t)tok * CC;
  float v0 = x[row + lane], v1 = x[row + lane + 64], v2 = x[row + lane + 128];
  float s = v0 + v1 + v2, ss = v0 * v0 + v1 * v1 + v2 * v2;
#pragma unroll
  for (int off = 1; off < 64; off <<= 1) {
    s += __shfl_xor(s, off, 64);
    ss += __shfl_xor(ss, off, 64);
  }
  float mean = s * (1.0f / CC);
  float rstd = rsqrtf(ss * (1.0f / CC) - mean * mean + 1e-5f);
  xn[row + lane]       = f2b((v0 - mean) * rstd * g[lane]       + b[lane]);
  xn[row + lane + 64]  = f2b((v1 - mean) * rstd * g[lane + 64]  + b[lane + 64]);
  xn[row + lane + 128] = f2b((v2 - mean) * rstd * g[lane + 128] + b[lane + 128]);
}

// ------------- K2: bias gather biasQ[h][query][key] (fp32) ------------------
__global__ __launch_bounds__(256) void k_biasq(const int* __restrict__ rpi,
                                               const float* __restrict__ rpb,
                                               float* __restrict__ biasQ) {
  int k = threadIdx.x;
  int h = blockIdx.x >> 8;
  int q = blockIdx.x & 255;
  biasQ[(size_t)blockIdx.x * 256 + k] = rpb[rpi[q * 256 + k] * NHEAD + h];
}

// ------- K2b: conv weight transpose to [tap][oc][ci] bf16 -------------------
__global__ __launch_bounds__(256) void k_wprep(const float* __restrict__ c1w,
                                               const float* __restrict__ c2w,
                                               bf16* __restrict__ wT1,
                                               bf16* __restrict__ wT2) {
  int i = blockIdx.x * 256 + threadIdx.x;   // 0 .. 110591
  {
    int tap = i / (64 * 192); int r = i % (64 * 192);
    int oc = r / 192, ci = r % 192;
    wT1[i] = f2b(c1w[(size_t)(tap * 192 + ci) * 64 + oc]);
  }
  {
    int tap = i / (192 * 64); int r = i % (192 * 64);
    int oc = r / 64, ci = r % 64;
    wT2[i] = f2b(c2w[(size_t)(tap * 64 + ci) * 192 + oc]);
  }
}

// ------- K2c: MLP weight transpose to n-major bf16 --------------------------
__global__ __launch_bounds__(256) void k_wprep2(const float* __restrict__ fc1w,
                                                const float* __restrict__ fc2w,
                                                bf16* __restrict__ wF1,
                                                bf16* __restrict__ wF2) {
  int i = blockIdx.x * 256 + threadIdx.x;   // 0 .. 147455
  {
    int n = i / 192, k = i % 192;           // wF1[n][k], n<768 k<192
    wF1[i] = f2b(fc1w[(size_t)k * 768 + n]);
  }
  {
    int n = i / 768, k = i % 768;           // wF2[n][k], n<192 k<768
    wF2[i] = f2b(fc2w[(size_t)k * 192 + n]);
  }
}

// ------- K2d: qkv/proj weight transpose to n-major bf16 ---------------------
__global__ __launch_bounds__(256) void k_wprep3(const float* __restrict__ qkvw,
                                                const float* __restrict__ projw,
                                                bf16* __restrict__ wQv,
                                                bf16* __restrict__ wP) {
  int i = blockIdx.x * 256 + threadIdx.x;   // 0 .. 147455 (grid 576)
  if (i < 576 * 192) {
    int n = i / 192, k = i % 192;           // wQv[n][k], n<576
    wQv[i] = f2b(qkvw[(size_t)k * 576 + n]);
  }
  if (i < 192 * 192) {
    int n = i / 192, k = i % 192;           // wP[n][k]
    wP[i] = f2b(projw[(size_t)k * 192 + n]);
  }
}

// --- K3: QKV GEMM via MFMA (N=576, K=192), gathered scatter store -----------
// grid TTOT/32, block 256 (4 waves). Wave w: cols w*144..+143 (9 tiles).
// 2 token-tiles per block: each weight fragment feeds 2 MFMA.
__global__ __launch_bounds__(256) void k_qkvg2(const bf16* __restrict__ xn,
                                               const bf16* __restrict__ wQv,
                                               const float* __restrict__ qb,
                                               bf16* __restrict__ Qg,
                                               bf16* __restrict__ Kg,
                                               bf16* __restrict__ Vg) {
  int tok0 = blockIdx.x * 32;
  int wave = threadIdx.x >> 6, lane = threadIdx.x & 63;
  int lm = lane & 15, lq = lane >> 4;
  const bf16* arow0 = xn + (size_t)(tok0 + lm) * CC + lq * 8;
  const bf16* arow1 = xn + (size_t)(tok0 + 16 + lm) * CC + lq * 8;
  float4v acc[9][2];
#pragma unroll
  for (int nt = 0; nt < 9; ++nt)
#pragma unroll
    for (int tt = 0; tt < 2; ++tt) acc[nt][tt] = (float4v){0.f, 0.f, 0.f, 0.f};
#pragma unroll
  for (int ks = 0; ks < 6; ++ks) {
    short8 af0 = *(const short8*)(arow0 + ks * 32);
    short8 af1 = *(const short8*)(arow1 + ks * 32);
#pragma unroll
    for (int nt = 0; nt < 9; ++nt) {
      int col = wave * 144 + nt * 16 + lm;
      short8 bfrag = *(const short8*)(wQv + (size_t)col * CC + ks * 32 + lq * 8);
      acc[nt][0] = __builtin_amdgcn_mfma_f32_16x16x32_bf16(af0, bfrag, acc[nt][0], 0, 0, 0);
      acc[nt][1] = __builtin_amdgcn_mfma_f32_16x16x32_bf16(af1, bfrag, acc[nt][1], 0, 0, 0);
    }
  }
  // per-(tt,reg) token -> gathered (window,head) coords
  size_t base[2][4];
#pragma unroll
  for (int tt = 0; tt < 2; ++tt)
#pragma unroll
    for (int reg = 0; reg < 4; ++reg) {
      int tg = tok0 + tt * 16 + lq * 4 + reg;
      int b = tg >> 14;
      int pix = tg & 16383;
      int gh = pix >> 7, gw = pix & 127;
      int hs = (gh + 120) & 127, wsx = (gw + 120) & 127;
      int wdx = (b << 6) + ((hs >> 4) << 3) + (wsx >> 4);
      int ndx = ((hs & 15) << 4) + (wsx & 15);
      base[tt][reg] = ((size_t)wdx * NHEAD) * NTOK * HD + (size_t)ndx * HD;
    }
#pragma unroll
  for (int nt = 0; nt < 9; ++nt) {
    int col = wave * 144 + nt * 16 + lm;
    float bias = qb[col];
    int sect = col / 192, within = col - sect * 192;
    int head = within >> 5, d = within & 31;
    bf16* dst = (sect == 0) ? Qg : (sect == 1) ? Kg : Vg;
    float scale = (sect == 0) ? SCALE_Q : 1.f;
#pragma unroll
    for (int tt = 0; tt < 2; ++tt)
#pragma unroll
      for (int reg = 0; reg < 4; ++reg) {
        dst[base[tt][reg] + (size_t)head * NTOK * HD + d] =
            f2b((acc[nt][tt][reg] + bias) * scale);
      }
  }
}

// --- K4: windowed attention via MFMA --------------------------------------
// grid = 1536*2 (wh, query-half). block 256 = 4 waves x 32 queries.
// S = Q*K^T (MFMA), full softmax per 16-row tile, P->LDS bf16, O = P*V (MFMA).
__global__ __launch_bounds__(256) void k_attn2(const bf16* __restrict__ Qg,
                                               const bf16* __restrict__ Kg,
                                               const bf16* __restrict__ Vg,
                                               const float* __restrict__ biasQ,
                                               bf16* __restrict__ AO) {
  __shared__ unsigned short PTw[4][16 * PSTR];  // 33,792 B (wave-private P tiles)
  __shared__ unsigned short VT[32 * PSTR];      // 16,896 B (V transposed)
  int wh = blockIdx.x >> 1, half = blockIdx.x & 1;
  int wdx = wh / NHEAD, h = wh - wdx * NHEAD;
  int wl = wdx & 63;
  int wr = wl >> 3, wc = wl & 7;
  int tid = threadIdx.x;
  int wave = tid >> 6, lane = tid & 63;
  int lm = lane & 15, lq = lane >> 4;
  int q0 = half * 128;

  // stage V^T: thread tid handles key row tid
  {
    const uint4* vp = (const uint4*)(Vg + ((size_t)wh * NTOK + tid) * HD);
    uint4 vv[4] = {vp[0], vp[1], vp[2], vp[3]};
#pragma unroll
    for (int i = 0; i < 4; ++i) {
      unsigned arr[4] = {vv[i].x, vv[i].y, vv[i].z, vv[i].w};
#pragma unroll
      for (int j = 0; j < 4; ++j) {
        int d = i * 8 + j * 2;
        VT[d * PSTR + tid]       = (unsigned short)(arr[j] & 0xffffu);
        VT[(d + 1) * PSTR + tid] = (unsigned short)(arr[j] >> 16);
      }
    }
  }
  __syncthreads();

  int wsk = (wc << 4) + lm;                       // lane's key col (w coord)
  int ridk_w = (wsk >= 112) + (wsk >= 120);
  unsigned short* PT = &PTw[wave][0];

  float4v oacc[2][2];
#pragma unroll
  for (int rt = 0; rt < 2; ++rt)
#pragma unroll
    for (int c2 = 0; c2 < 2; ++c2) oacc[rt][c2] = (float4v){0.f, 0.f, 0.f, 0.f};
  float linv[2][4];

#pragma unroll
  for (int rt = 0; rt < 2; ++rt) {
    int qrow = q0 + wave * 32 + rt * 16;
    short8 aq = *(const short8*)(Qg + ((size_t)wh * NTOK + qrow + lm) * HD + lq * 8);
    float4v sacc[16];
#pragma unroll
    for (int ct = 0; ct < 16; ++ct) sacc[ct] = (float4v){0.f, 0.f, 0.f, 0.f};
#pragma unroll
    for (int ct = 0; ct < 16; ++ct) {
      short8 kf = *(const short8*)(Kg + ((size_t)wh * NTOK + ct * 16 + lm) * HD + lq * 8);
      sacc[ct] = __builtin_amdgcn_mfma_f32_16x16x32_bf16(aq, kf, sacc[ct], 0, 0, 0);
    }
    // softmax over 256 keys, rows lq*4+reg of this 16-row tile
#pragma unroll
    for (int reg = 0; reg < 4; ++reg) {
      int nq = qrow + lq * 4 + reg;
      int hsq = (wr << 4) + (nq >> 4), wsq = (wc << 4) + (nq & 15);
      int ridq = ((hsq >= 112) + (hsq >= 120)) * 3 + ((wsq >= 112) + (wsq >= 120));
      const float* bq = biasQ + ((size_t)(h * 256 + nq)) * 256 + lm;
      float sv[16];
      float mx = -1.0e30f;
#pragma unroll
      for (int ct = 0; ct < 16; ++ct) {
        int hsk = (wr << 4) + ct;
        int ridk = ((hsk >= 112) + (hsk >= 120)) * 3 + ridk_w;
        float s = sacc[ct][reg] + bq[ct * 16] + ((ridk != ridq) ? -100.f : 0.f);
        sv[ct] = s;
        mx = fmaxf(mx, s);
      }
#pragma unroll
      for (int off = 1; off < 16; off <<= 1) mx = fmaxf(mx, __shfl_xor(mx, off, 64));
      float l = 0.f;
#pragma unroll
      for (int ct = 0; ct < 16; ++ct) {
        float p = __expf(sv[ct] - mx);
        l += p;
        PT[(lq * 4 + reg) * PSTR + ct * 16 + lm] = f2bu(p);
      }
#pragma unroll
      for (int off = 1; off < 16; off <<= 1) l += __shfl_xor(l, off, 64);
      linv[rt][reg] = 1.f / l;
    }
    // PV for this row tile: A = P rows (wave-private, in-wave LDS ordering)
#pragma unroll
    for (int kb = 0; kb < 8; ++kb) {
      short8 pf = *(const short8*)&PT[lm * PSTR + kb * 32 + lq * 8];
#pragma unroll
      for (int c2 = 0; c2 < 2; ++c2) {
        short8 vf = *(const short8*)&VT[(c2 * 16 + lm) * PSTR + kb * 32 + lq * 8];
        oacc[rt][c2] = __builtin_amdgcn_mfma_f32_16x16x32_bf16(pf, vf, oacc[rt][c2], 0, 0, 0);
      }
    }
  }
  // write AO
#pragma unroll
  for (int rt = 0; rt < 2; ++rt)
#pragma unroll
    for (int c2 = 0; c2 < 2; ++c2) {
      int d = c2 * 16 + lm;
#pragma unroll
      for (int reg = 0; reg < 4; ++reg) {
        int nq = q0 + wave * 32 + rt * 16 + lq * 4 + reg;
        AO[((size_t)wdx * NTOK + nq) * CC + h * HD + d] =
            f2b(oacc[rt][c2][reg] * linv[rt][reg]);
      }
    }
}

// --- K5: proj GEMM via MFMA (N=192, K=192) + shift-reverse + x residual -----
// grid TTOT/32 (win-order rows), block 256 (4 waves). Wave w: cols w*48..+47.
// 2 token-tiles per block: each wP fragment feeds 2 MFMA.
__global__ __launch_bounds__(256) void k_proj2(const bf16* __restrict__ AO,
                                               const bf16* __restrict__ wP,
                                               const float* __restrict__ pb,
                                               const float* __restrict__ x,
                                               float* __restrict__ y) {
  int r0 = blockIdx.x * 32;
  int wave = threadIdx.x >> 6, lane = threadIdx.x & 63;
  int lm = lane & 15, lq = lane >> 4;
  const bf16* arow0 = AO + (size_t)(r0 + lm) * CC + lq * 8;
  const bf16* arow1 = AO + (size_t)(r0 + 16 + lm) * CC + lq * 8;
  float4v acc[3][2];
#pragma unroll
  for (int nt = 0; nt < 3; ++nt)
#pragma unroll
    for (int tt = 0; tt < 2; ++tt) acc[nt][tt] = (float4v){0.f, 0.f, 0.f, 0.f};
#pragma unroll
  for (int ks = 0; ks < 6; ++ks) {
    short8 af0 = *(const short8*)(arow0 + ks * 32);
    short8 af1 = *(const short8*)(arow1 + ks * 32);
#pragma unroll
    for (int nt = 0; nt < 3; ++nt) {
      int col = wave * 48 + nt * 16 + lm;
      short8 bfrag = *(const short8*)(wP + (size_t)col * CC + ks * 32 + lq * 8);
      acc[nt][0] = __builtin_amdgcn_mfma_f32_16x16x32_bf16(af0, bfrag, acc[nt][0], 0, 0, 0);
      acc[nt][1] = __builtin_amdgcn_mfma_f32_16x16x32_bf16(af1, bfrag, acc[nt][1], 0, 0, 0);
    }
  }
  size_t drow[2][4];
#pragma unroll
  for (int tt = 0; tt < 2; ++tt)
#pragma unroll
    for (int reg = 0; reg < 4; ++reg) {
      int r = r0 + tt * 16 + lq * 4 + reg;
      int wdx = r >> 8, n = r & 255;
      int wb = wdx >> 6, wl = wdx & 63;
      int hs = ((wl >> 3) << 4) + (n >> 4);
      int wsx = ((wl & 7) << 4) + (n & 15);
      int gh = (hs + SSH) & 127, gw = (wsx + SSH) & 127;
      drow[tt][reg] = ((size_t)wb * HWPIX + (size_t)gh * WWID + gw) * CC;
    }
#pragma unroll
  for (int nt = 0; nt < 3; ++nt) {
    int col = wave * 48 + nt * 16 + lm;
    float bias = pb[col];
#pragma unroll
    for (int tt = 0; tt < 2; ++tt)
#pragma unroll
      for (int reg = 0; reg < 4; ++reg) {
        y[drow[tt][reg] + col] = x[drow[tt][reg] + col] + acc[nt][tt][reg] + bias;
      }
  }
}

// ---- K6: conv3x3 192->64 + GELU via MFMA implicit GEMM ---------------------
__global__ __launch_bounds__(256) void k_conv1m(const bf16* __restrict__ xn,
                                                const bf16* __restrict__ wT1,
                                                const float* __restrict__ c1b,
                                                bf16* __restrict__ cv1) {
  int bi = blockIdx.x;
  int seg = bi & 1, hh = (bi >> 1) & 127, b = bi >> 8;
  int px0 = seg * 64;
  int wave = threadIdx.x >> 6, lane = threadIdx.x & 63;
  int lm = lane & 15, lq = lane >> 4;
  int oc = wave * 16 + lm;
  float4v acc[4];
#pragma unroll
  for (int t = 0; t < 4; ++t) acc[t] = (float4v){0.f, 0.f, 0.f, 0.f};
#pragma unroll
  for (int tap = 0; tap < 9; ++tap) {
    int kh = tap / 3, kw = tap % 3;
    int gh = hh + kh - 1;
    bool rowok = ((unsigned)gh < 128u);
    const bf16* wrow = wT1 + ((size_t)tap * 64 + oc) * CC + lq * 8;
    const bf16* xrow = xn + ((size_t)b * HWPIX + (size_t)gh * WWID) * CC + lq * 8;
#pragma unroll
    for (int ks = 0; ks < 6; ++ks) {
      short8 bfrag = *(const short8*)(wrow + ks * 32);
#pragma unroll
      for (int t = 0; t < 4; ++t) {
        int px = px0 + t * 16 + lm + kw - 1;
        short8 afrag = ld8z(xrow + (size_t)px * CC + ks * 32,
                            rowok && ((unsigned)px < 128u));
        acc[t] = __builtin_amdgcn_mfma_f32_16x16x32_bf16(afrag, bfrag, acc[t], 0, 0, 0);
      }
    }
  }
  float bias = c1b[oc];
#pragma unroll
  for (int t = 0; t < 4; ++t) {
    int pxb = px0 + t * 16 + lq * 4;
    size_t base = ((size_t)b * HWPIX + (size_t)hh * WWID + pxb) * 64 + oc;
    cv1[base]       = f2b(gelu_exact(acc[t][0] + bias));
    cv1[base + 64]  = f2b(gelu_exact(acc[t][1] + bias));
    cv1[base + 128] = f2b(gelu_exact(acc[t][2] + bias));
    cv1[base + 192] = f2b(gelu_exact(acc[t][3] + bias));
  }
}

// ---- K7: conv3x3 64->192 + bias via MFMA implicit GEMM ---------------------
__global__ __launch_bounds__(256) void k_conv2m(const bf16* __restrict__ cv1,
                                                const bf16* __restrict__ wT2,
                                                const float* __restrict__ c2b,
                                                bf16* __restrict__ cv2) {
  int bi = blockIdx.x;
  int seg = bi & 1, hh = (bi >> 1) & 127, b = bi >> 8;
  int px0 = seg * 64;
  int wave = threadIdx.x >> 6, lane = threadIdx.x & 63;
  int lm = lane & 15, lq = lane >> 4;
  float4v acc[3][4];
#pragma unroll
  for (int nt = 0; nt < 3; ++nt)
#pragma unroll
    for (int t = 0; t < 4; ++t) acc[nt][t] = (float4v){0.f, 0.f, 0.f, 0.f};
#pragma unroll
  for (int tap = 0; tap < 9; ++tap) {
    int kh = tap / 3, kw = tap % 3;
    int gh = hh + kh - 1;
    bool rowok = ((unsigned)gh < 128u);
    const bf16* xrow = cv1 + ((size_t)b * HWPIX + (size_t)gh * WWID) * 64 + lq * 8;
#pragma unroll
    for (int ks = 0; ks < 2; ++ks) {
      short8 bfrag[3];
#pragma unroll
      for (int nt = 0; nt < 3; ++nt) {
        int oc = wave * 48 + nt * 16 + lm;
        bfrag[nt] = *(const short8*)(wT2 + ((size_t)tap * 192 + oc) * 64 + ks * 32 + lq * 8);
      }
#pragma unroll
      for (int t = 0; t < 4; ++t) {
        int px = px0 + t * 16 + lm + kw - 1;
        short8 afrag = ld8z(xrow + (size_t)px * 64 + ks * 32,
                            rowok && ((unsigned)px < 128u));
#pragma unroll
        for (int nt = 0; nt < 3; ++nt)
          acc[nt][t] = __builtin_amdgcn_mfma_f32_16x16x32_bf16(afrag, bfrag[nt], acc[nt][t], 0, 0, 0);
      }
    }
  }
#pragma unroll
  for (int nt = 0; nt < 3; ++nt) {
    int oc = wave * 48 + nt * 16 + lm;
    float bias = c2b[oc];
#pragma unroll
    for (int t = 0; t < 4; ++t) {
      int pxb = px0 + t * 16 + lq * 4;
      size_t base = ((size_t)b * HWPIX + (size_t)hh * WWID + pxb) * CC + oc;
      cv2[base]           = f2b(acc[nt][t][0] + bias);
      cv2[base + CC]      = f2b(acc[nt][t][1] + bias);
      cv2[base + 2 * CC]  = f2b(acc[nt][t][2] + bias);
      cv2[base + 3 * CC]  = f2b(acc[nt][t][3] + bias);
    }
  }
}

// ---------------- K8: global average pool (sum into pooled, pre-zeroed) ----
__global__ __launch_bounds__(192) void k_pool(const bf16* __restrict__ cv2,
                                              float* __restrict__ pooled) {
  int t = threadIdx.x;                        // channel
  int b = blockIdx.x >> 7;
  int pc = blockIdx.x & 127;                  // 128-pixel chunk
  const bf16* base = cv2 + ((size_t)b * HWPIX + (size_t)pc * 128) * CC + t;
  float s = 0.f;
#pragma unroll 4
  for (int p = 0; p < 128; ++p) s += b2f(base[(size_t)p * CC]);
  atomicAdd(&pooled[b * CC + t], s);
}

// ---------------- K9: channel attention weights ----------------
__global__ __launch_bounds__(192) void k_ca(const float* __restrict__ pooled,
                                            const float* __restrict__ w1,
                                            const float* __restrict__ b1,
                                            const float* __restrict__ w2,
                                            const float* __restrict__ b2,
                                            float* __restrict__ ca) {
  __shared__ float pld[CC];
  __shared__ float t1[6];
  int t = threadIdx.x, b = blockIdx.x;
  pld[t] = pooled[b * CC + t] * (1.0f / HWPIX);
  __syncthreads();
  if (t < 6) {
    float s = b1[t];
    for (int c = 0; c < CC; ++c) s += pld[c] * w1[c * 6 + t];
    t1[t] = fmaxf(s, 0.f);
  }
  __syncthreads();
  float s = b2[t];
#pragma unroll
  for (int k = 0; k < 6; ++k) s += t1[k] * w2[k * CC + t];
  ca[b * CC + t] = 1.f / (1.f + __expf(-s));
}

// --- K11: fused LN2 + MLP, LDS-staged weights, double-buffered --------------
// grid TTOT/32, block 256 (4 waves), 32 tokens/block, 2 blocks/CU.
// Weights are staged into LDS in 12.3 KB chunks (192 rows x 32 k) by 12
// global_load_lds dwordx4 issues per chunk (3/wave, async DMA), double-
// buffered: stage chunk t+1 -> compute chunk t from LDS -> __syncthreads()
// (hipcc emits vmcnt(0)+barrier = the T3-minimum drain). LDS reads are made
// ~conflict-free by pre-swizzling the GLOBAL source (c' ^= (r>>1)&3, rule #21:
// LDS stays linear): 16 lanes -> 8 banks x2 = free.
// Phase 1 (fc1+GELU, chunks 0..23 = 4 p x 6 ks): swapped-operand MFMA, h to
// LDS packed. Phase 2 (fc2+residual, chunks 24..47): A=h rows, B=staged wF2.
// ynl (LN output, 12.8 KB) aliases the weight buffers (dead after tf hoist).
// LDS: 24,576(wbuf) + 49,664(h) = 74,240 B -> 2 blocks/CU.
__global__ __launch_bounds__(256, 2) void k_mlp(const float* __restrict__ y,
                                                const bf16* __restrict__ cv2,
                                                const float* __restrict__ ca,
                                                const float* __restrict__ g2,
                                                const float* __restrict__ bn2,
                                                const bf16* __restrict__ wF1,
                                                const bf16* __restrict__ wF2,
                                                const float* __restrict__ fb1,
                                                const float* __restrict__ fb2,
                                                float* __restrict__ out) {
  __shared__ unsigned short sws[2][6144];     // 24,576 B weight double-buffer
  __shared__ unsigned short hl[32 * HSTR];    // 49,664 B
  unsigned short* ynl = &sws[0][0];           // [32][YSTR] alias (<=12,800 B)
  int tok0 = blockIdx.x * 32;
  int wave = threadIdx.x >> 6, lane = threadIdx.x & 63;
  int lm = lane & 15, lq = lane >> 4;
  const float* cab = ca + (tok0 >> 14) * CC;

  // ---- phase 0: LN2 with conv-branch fold, result -> ynl (LDS bf16) ----
  {
    float gg0 = g2[lane], gg1 = g2[lane + 64], gg2 = g2[lane + 128];
    float bb0 = bn2[lane], bb1 = bn2[lane + 64], bb2 = bn2[lane + 128];
    float c0 = cab[lane] * CONV_SC, c1 = cab[lane + 64] * CONV_SC, c2 = cab[lane + 128] * CONV_SC;
#pragma unroll
    for (int t = 0; t < 8; ++t) {
      int tl = wave * 8 + t;
      size_t row = (size_t)(tok0 + tl) * CC;
      float v0 = y[row + lane]       + b2f(cv2[row + lane])       * c0;
      float v1 = y[row + lane + 64]  + b2f(cv2[row + lane + 64])  * c1;
      float v2 = y[row + lane + 128] + b2f(cv2[row + lane + 128]) * c2;
      float s = v0 + v1 + v2, ss = v0 * v0 + v1 * v1 + v2 * v2;
#pragma unroll
      for (int off = 1; off < 64; off <<= 1) {
        s += __shfl_xor(s, off, 64);
        ss += __shfl_xor(ss, off, 64);
      }
      float mean = s * (1.0f / CC);
      float rstd = rsqrtf(ss * (1.0f / CC) - mean * mean + 1e-5f);
      ynl[tl * YSTR + lane]       = f2bu((v0 - mean) * rstd * gg0 + bb0);
      ynl[tl * YSTR + lane + 64]  = f2bu((v1 - mean) * rstd * gg1 + bb1);
      ynl[tl * YSTR + lane + 128] = f2bu((v2 - mean) * rstd * gg2 + bb2);
    }
  }
  __syncthreads();

  // hoist the 12 token B-fragments into registers (48 VGPR), freeing ynl LDS
  short8 tf[2][6];
#pragma unroll
  for (int tt = 0; tt < 2; ++tt)
#pragma unroll
    for (int ks = 0; ks < 6; ++ks)
      tf[tt][ks] = *(const short8*)&ynl[(tt * 16 + lm) * YSTR + ks * 32 + lq * 8];
  __syncthreads();   // all frag reads drained before staging overwrites ynl

  // ---- staging setup ----
  // chunk layout: 192 rows x 4 chunks(16B). lane -> idx16 = seg*64+lane,
  // r = seg*16 + (lane>>2), c' = lane&3; source k-chunk c = c' ^ ((r>>1)&3).
  // (r>>1)&3 reduces to (lane>>3)&3 since seg*16 is a multiple of 8.
  const char* gw1 = (const char*)wF1;
  const char* gw2 = (const char*)wF2;
  int rj0 = wave * 48 + (lane >> 2);                       // + jj*16
  int swzb = (((lane & 3) ^ ((lane >> 3) & 3)) << 4);      // byte offset in k
  char* lb[2] = {(char*)&sws[0][0] + wave * 3072, (char*)&sws[1][0] + wave * 3072};
  int swzr = (lm >> 1) & 3;                                // read-side swizzle

  // stage phase-1 chunk (p,ks) into buffer b
  auto stage1 = [&](int p, int ks, int b) {
#pragma unroll
    for (int jj = 0; jj < 3; ++jj) {
      int r = rj0 + jj * 16;
      glds16(gw1 + (size_t)(p * 192 + r) * 384 + ks * 64 + swzb, lb[b] + jj * 1024);
    }
  };
  // stage phase-2 chunk ks into buffer b
  auto stage2 = [&](int ks, int b) {
#pragma unroll
    for (int jj = 0; jj < 3; ++jj) {
      int r = rj0 + jj * 16;
      glds16(gw2 + (size_t)r * 1536 + ks * 64 + swzb, lb[b] + jj * 1024);
    }
  };

  stage1(0, 0, 0);
  __syncthreads();   // drains vmcnt -> chunk 0 resident

  // ---- phase 1: h = GELU(yn @ fc1 + b), weights from LDS ----
#pragma unroll
  for (int p = 0; p < 4; ++p) {
    float4v acc[2][3];
#pragma unroll
    for (int tt = 0; tt < 2; ++tt)
#pragma unroll
      for (int nt = 0; nt < 3; ++nt) acc[tt][nt] = (float4v){0.f, 0.f, 0.f, 0.f};
#pragma unroll
    for (int ks = 0; ks < 6; ++ks) {
      int t = p * 6 + ks, cur = t & 1, nxt = cur ^ 1;
      if (t < 23) stage1((t + 1) / 6, (t + 1) % 6, nxt);
      else stage2(0, nxt);
      const unsigned short* wb = sws[cur];
      short8 af[3];
#pragma unroll
      for (int nt = 0; nt < 3; ++nt) {
        int r = wave * 48 + nt * 16 + lm;
        af[nt] = *(const short8*)&wb[(r << 5) + ((lq ^ swzr) << 3)];
      }
#pragma unroll
      for (int nt = 0; nt < 3; ++nt) {
        acc[0][nt] = __builtin_amdgcn_mfma_f32_16x16x32_bf16(af[nt], tf[0][ks], acc[0][nt], 0, 0, 0);
        acc[1][nt] = __builtin_amdgcn_mfma_f32_16x16x32_bf16(af[nt], tf[1][ks], acc[1][nt], 0, 0, 0);
      }
      if (ks == 5) {
#pragma unroll
        for (int nt = 0; nt < 3; ++nt) {
          int n0 = p * 192 + wave * 48 + nt * 16 + lq * 4;   // 4 consecutive n
          float4 b4 = *(const float4*)(fb1 + n0);
#pragma unroll
          for (int tt = 0; tt < 2; ++tt) {
            unsigned short u0 = f2bu(gelu_exact(acc[tt][nt][0] + b4.x));
            unsigned short u1 = f2bu(gelu_exact(acc[tt][nt][1] + b4.y));
            unsigned short u2 = f2bu(gelu_exact(acc[tt][nt][2] + b4.z));
            unsigned short u3 = f2bu(gelu_exact(acc[tt][nt][3] + b4.w));
            uint2 pk;
            pk.x = (unsigned)u0 | ((unsigned)u1 << 16);
            pk.y = (unsigned)u2 | ((unsigned)u3 << 16);
            *(uint2*)&hl[(size_t)(tt * 16 + lm) * HSTR + n0] = pk;
          }
        }
      }
      __syncthreads();
    }
  }

  // ---- phase 2: out = h @ fc2 + (y + cv2*ca*0.01) + b, weights from LDS ----
  float4v acc2[2][3];
#pragma unroll
  for (int tt = 0; tt < 2; ++tt)
#pragma unroll
    for (int nt = 0; nt < 3; ++nt) acc2[tt][nt] = (float4v){0.f, 0.f, 0.f, 0.f};
#pragma unroll
  for (int ks = 0; ks < 24; ++ks) {
    int t = 24 + ks, cur = t & 1, nxt = cur ^ 1;
    if (ks < 23) stage2(ks + 1, nxt);
    const unsigned short* wb = sws[cur];
    short8 h0 = *(const short8*)&hl[(size_t)lm * HSTR + ks * 32 + lq * 8];
    short8 h1 = *(const short8*)&hl[(size_t)(16 + lm) * HSTR + ks * 32 + lq * 8];
    short8 wf[3];
#pragma unroll
    for (int nt = 0; nt < 3; ++nt) {
      int r = wave * 48 + nt * 16 + lm;
      wf[nt] = *(const short8*)&wb[(r << 5) + ((lq ^ swzr) << 3)];
    }
#pragma unroll
    for (int nt = 0; nt < 3; ++nt) {
      acc2[0][nt] = __builtin_amdgcn_mfma_f32_16x16x32_bf16(h0, wf[nt], acc2[0][nt], 0, 0, 0);
      acc2[1][nt] = __builtin_amdgcn_mfma_f32_16x16x32_bf16(h1, wf[nt], acc2[1][nt], 0, 0, 0);
    }
    if (ks < 23) __syncthreads();
  }
#pragma unroll
  for (int tt = 0; tt < 2; ++tt)
#pragma unroll
    for (int nt = 0; nt < 3; ++nt) {
      int col = wave * 48 + nt * 16 + lm;
      float bias = fb2[col];
      float cas = cab[col] * CONV_SC;
#pragma unroll
      for (int reg = 0; reg < 4; ++reg) {
        int tok = tok0 + tt * 16 + lq * 4 + reg;
        size_t idx = (size_t)tok * CC + col;
        out[idx] = y[idx] + b2f(cv2[idx]) * cas + acc2[tt][nt][reg] + bias;
      }
    }
}

extern "C" void kernel_launch(void* const* d_in, const int* in_sizes, int n_in,
                              void* d_out, int out_size, void* d_ws, size_t ws_size,
                              hipStream_t stream) {
  const float* x      = (const float*)d_in[0];
  const float* qkv_w  = (const float*)d_in[1];
  const float* qkv_b  = (const float*)d_in[2];
  const float* proj_w = (const float*)d_in[3];
  const float* proj_b = (const float*)d_in[4];
  const float* rpb    = (const float*)d_in[5];
  const float* n1w    = (const float*)d_in[6];
  const float* n1b    = (const float*)d_in[7];
  const float* n2w    = (const float*)d_in[8];
  const float* n2b    = (const float*)d_in[9];
  const float* c1w    = (const float*)d_in[10];
  const float* c1b    = (const float*)d_in[11];
  const float* c2w    = (const float*)d_in[12];
  const float* c2b    = (const float*)d_in[13];
  const float* ca1w   = (const float*)d_in[14];
  const float* ca1b   = (const float*)d_in[15];
  const float* ca2w   = (const float*)d_in[16];
  const float* ca2b   = (const float*)d_in[17];
  const float* fc1w   = (const float*)d_in[18];
  const float* fc1b   = (const float*)d_in[19];
  const float* fc2w   = (const float*)d_in[20];
  const float* fc2b   = (const float*)d_in[21];
  const int*   rpi    = (const int*)d_in[22];
  (void)in_sizes; (void)n_in; (void)out_size; (void)ws_size;

  // ---- workspace layout: peak ~212.6 MB (< 256 MiB) ----
  char* wsb = (char*)d_ws;
  bf16*  xn    = (bf16*)(wsb + 0);            // 25,165,824
  float* biasQ = (float*)(wsb + 25165824);    //  1,572,864
  bf16*  Qg    = (bf16*)(wsb + 26738688);     // 25,165,824
  bf16*  Kg    = (bf16*)(wsb + 51904512);     // 25,165,824
  bf16*  Vg    = (bf16*)(wsb + 77070336);     // 25,165,824
  bf16*  AO    = (bf16*)(wsb + 102236160);    // 25,165,824
  float* y     = (float*)(wsb + 127401984);   // 50,331,648
  bf16*  cv1   = (bf16*)(wsb + 177733632);    //  8,388,608
  bf16*  cv2   = (bf16*)(wsb + 186122240);    // 25,165,824
  float* pool  = (float*)(wsb + 211288064);   //      3,072
  float* cavec = (float*)(wsb + 211291136);   //      3,072
  bf16*  wT1   = (bf16*)(wsb + 211294208);    //    221,184  [9][64][192]
  bf16*  wT2   = (bf16*)(wsb + 211515392);    //    221,184  [9][192][64]
  bf16*  wF1   = (bf16*)(wsb + 211736576);    //    294,912  [768][192]
  bf16*  wF2   = (bf16*)(wsb + 212031488);    //    294,912  [192][768]
  bf16*  wQv   = (bf16*)(wsb + 212326400);    //    221,184  [576][192]
  bf16*  wP    = (bf16*)(wsb + 212547584);    //     73,728  [192][192]
  float* out   = (float*)d_out;               // end 212,621,312

  k_ln1<<<TTOT / 4, 256, 0, stream>>>(x, n1w, n1b, xn);
  k_biasq<<<NHEAD * NTOK, 256, 0, stream>>>(rpi, rpb, biasQ);
  k_wprep<<<432, 256, 0, stream>>>(c1w, c2w, wT1, wT2);
  k_wprep2<<<576, 256, 0, stream>>>(fc1w, fc2w, wF1, wF2);
  k_wprep3<<<576, 256, 0, stream>>>(qkv_w, proj_w, wQv, wP);
  k_qkvg2<<<TTOT / 32, 256, 0, stream>>>(xn, wQv, qkv_b, Qg, Kg, Vg);
  k_attn2<<<BB * 64 * NHEAD * 2, 256, 0, stream>>>(Qg, Kg, Vg, biasQ, AO);
  k_proj2<<<TTOT / 32, 256, 0, stream>>>(AO, wP, proj_b, x, y);
  k_conv1m<<<1024, 256, 0, stream>>>(xn, wT1, c1b, cv1);
  k_conv2m<<<1024, 256, 0, stream>>>(cv1, wT2, c2b, cv2);
  hipMemsetAsync(pool, 0, BB * CC * sizeof(float), stream);
  k_pool<<<512, 192, 0, stream>>>(cv2, pool);
  k_ca<<<BB, 192, 0, stream>>>(pool, ca1w, ca1b, ca2w, ca2b, cavec);
  k_mlp<<<TTOT / 32, 256, 0, stream>>>(y, cv2, cavec, n2w, n2b,
                                       wF1, wF2, fc1b, fc2b, out);
}

// Round 6
// 820.089 us; speedup vs baseline: 1.2659x; 1.0000x over previous
//
#include <hip/hip_runtime.h>
#include <hip/hip_bf16.h>
#include <cstdint>
#include <cstddef>

#define BB 4
#define CC 192
#define NHEAD 6
#define WSZ 16
#define SSH 8
#define NTOK 256
#define HD 32
#define HWPIX 16384
#define TTOT 65536
#define WWID 128
#define SCALE_Q 0.17677669529663687f
#define CONV_SC 0.01f
#define PSTR 264   // attn LDS row stride (shorts): 16B-aligned, <=2-way banks

typedef __hip_bfloat16 bf16;
typedef __attribute__((ext_vector_type(8))) short short8;
typedef __attribute__((ext_vector_type(4))) float float4v;

__device__ __forceinline__ float b2f(bf16 v) { return __bfloat162float(v); }
__device__ __forceinline__ bf16 f2b(float v) { return __float2bfloat16(v); }
__device__ __forceinline__ unsigned short f2bu(float f) {
  bf16 h = __float2bfloat16(f);
  return *reinterpret_cast<unsigned short*>(&h);
}
__device__ __forceinline__ float gelu_exact(float x) {
  return 0.5f * x * (1.0f + erff(x * 0.7071067811865475f));
}
__device__ __forceinline__ short8 ld8z(const bf16* p, bool ok) {
  if (ok) return *(const short8*)p;
  short8 z = {0, 0, 0, 0, 0, 0, 0, 0};
  return z;
}
// async global->LDS 16B per lane: LDS dest = wave-uniform base + lane*16,
// global source is per-lane. size must be literal 16.
__device__ __forceinline__ void glds16(const void* g, void* l) {
  __builtin_amdgcn_global_load_lds(
      (const __attribute__((address_space(1))) unsigned int*)g,
      (__attribute__((address_space(3))) unsigned int*)l, 16, 0, 0);
}

// ---------------- K1: LayerNorm1 (x fp32 -> xn bf16). 1 wave per token -----
__global__ __launch_bounds__(256) void k_ln1(const float* __restrict__ x,
                                             const float* __restrict__ g,
                                             const float* __restrict__ b,
                                             bf16* __restrict__ xn) {
  int wv = threadIdx.x >> 6, lane = threadIdx.x & 63;
  int tok = blockIdx.x * 4 + wv;
  size_t row = (size_t)tok * CC;
  float v0 = x[row + lane], v1 = x[row + lane + 64], v2 = x[row + lane + 128];
  float s = v0 + v1 + v2, ss = v0 * v0 + v1 * v1 + v2 * v2;
#pragma unroll
  for (int off = 1; off < 64; off <<= 1) {
    s += __shfl_xor(s, off, 64);
    ss += __shfl_xor(ss, off, 64);
  }
  float mean = s * (1.0f / CC);
  float rstd = rsqrtf(ss * (1.0f / CC) - mean * mean + 1e-5f);
  xn[row + lane]       = f2b((v0 - mean) * rstd * g[lane]       + b[lane]);
  xn[row + lane + 64]  = f2b((v1 - mean) * rstd * g[lane + 64]  + b[lane + 64]);
  xn[row + lane + 128] = f2b((v2 - mean) * rstd * g[lane + 128] + b[lane + 128]);
}

// ------------- K2: bias gather biasQ[h][query][key] (fp32) ------------------
__global__ __launch_bounds__(256) void k_biasq(const int* __restrict__ rpi,
                                               const float* __restrict__ rpb,
                                               float* __restrict__ biasQ) {
  int k = threadIdx.x;
  int h = blockIdx.x >> 8;
  int q = blockIdx.x & 255;
  biasQ[(size_t)blockIdx.x * 256 + k] = rpb[rpi[q * 256 + k] * NHEAD + h];
}

// ------- K2b: conv weight transpose to [tap][oc][ci] bf16 -------------------
__global__ __launch_bounds__(256) void k_wprep(const float* __restrict__ c1w,
                                               const float* __restrict__ c2w,
                                               bf16* __restrict__ wT1,
                                               bf16* __restrict__ wT2) {
  int i = blockIdx.x * 256 + threadIdx.x;   // 0 .. 110591
  {
    int tap = i / (64 * 192); int r = i % (64 * 192);
    int oc = r / 192, ci = r % 192;
    wT1[i] = f2b(c1w[(size_t)(tap * 192 + ci) * 64 + oc]);
  }
  {
    int tap = i / (192 * 64); int r = i % (192 * 64);
    int oc = r / 64, ci = r % 64;
    wT2[i] = f2b(c2w[(size_t)(tap * 64 + ci) * 192 + oc]);
  }
}

// ------- K2c: MLP weight transpose to n-major bf16 --------------------------
__global__ __launch_bounds__(256) void k_wprep2(const float* __restrict__ fc1w,
                                                const float* __restrict__ fc2w,
                                                bf16* __restrict__ wF1,
                                                bf16* __restrict__ wF2) {
  int i = blockIdx.x * 256 + threadIdx.x;   // 0 .. 147455
  {
    int n = i / 192, k = i % 192;           // wF1[n][k], n<768 k<192
    wF1[i] = f2b(fc1w[(size_t)k * 768 + n]);
  }
  {
    int n = i / 768, k = i % 768;           // wF2[n][k], n<192 k<768
    wF2[i] = f2b(fc2w[(size_t)k * 192 + n]);
  }
}

// ------- K2d: qkv/proj weight transpose to n-major bf16 ---------------------
__global__ __launch_bounds__(256) void k_wprep3(const float* __restrict__ qkvw,
                                                const float* __restrict__ projw,
                                                bf16* __restrict__ wQv,
                                                bf16* __restrict__ wP) {
  int i = blockIdx.x * 256 + threadIdx.x;   // 0 .. 147455 (grid 576)
  if (i < 576 * 192) {
    int n = i / 192, k = i % 192;           // wQv[n][k], n<576
    wQv[i] = f2b(qkvw[(size_t)k * 576 + n]);
  }
  if (i < 192 * 192) {
    int n = i / 192, k = i % 192;           // wP[n][k]
    wP[i] = f2b(projw[(size_t)k * 192 + n]);
  }
}

// --- K3: QKV GEMM via MFMA (N=576, K=192), gathered scatter store -----------
// grid TTOT/32, block 256 (4 waves). Wave w: cols w*144..+143 (9 tiles).
// 2 token-tiles per block: each weight fragment feeds 2 MFMA.
__global__ __launch_bounds__(256) void k_qkvg2(const bf16* __restrict__ xn,
                                               const bf16* __restrict__ wQv,
                                               const float* __restrict__ qb,
                                               bf16* __restrict__ Qg,
                                               bf16* __restrict__ Kg,
                                               bf16* __restrict__ Vg) {
  int tok0 = blockIdx.x * 32;
  int wave = threadIdx.x >> 6, lane = threadIdx.x & 63;
  int lm = lane & 15, lq = lane >> 4;
  const bf16* arow0 = xn + (size_t)(tok0 + lm) * CC + lq * 8;
  const bf16* arow1 = xn + (size_t)(tok0 + 16 + lm) * CC + lq * 8;
  float4v acc[9][2];
#pragma unroll
  for (int nt = 0; nt < 9; ++nt)
#pragma unroll
    for (int tt = 0; tt < 2; ++tt) acc[nt][tt] = (float4v){0.f, 0.f, 0.f, 0.f};
#pragma unroll
  for (int ks = 0; ks < 6; ++ks) {
    short8 af0 = *(const short8*)(arow0 + ks * 32);
    short8 af1 = *(const short8*)(arow1 + ks * 32);
#pragma unroll
    for (int nt = 0; nt < 9; ++nt) {
      int col = wave * 144 + nt * 16 + lm;
      short8 bfrag = *(const short8*)(wQv + (size_t)col * CC + ks * 32 + lq * 8);
      acc[nt][0] = __builtin_amdgcn_mfma_f32_16x16x32_bf16(af0, bfrag, acc[nt][0], 0, 0, 0);
      acc[nt][1] = __builtin_amdgcn_mfma_f32_16x16x32_bf16(af1, bfrag, acc[nt][1], 0, 0, 0);
    }
  }
  // per-(tt,reg) token -> gathered (window,head) coords
  size_t base[2][4];
#pragma unroll
  for (int tt = 0; tt < 2; ++tt)
#pragma unroll
    for (int reg = 0; reg < 4; ++reg) {
      int tg = tok0 + tt * 16 + lq * 4 + reg;
      int b = tg >> 14;
      int pix = tg & 16383;
      int gh = pix >> 7, gw = pix & 127;
      int hs = (gh + 120) & 127, wsx = (gw + 120) & 127;
      int wdx = (b << 6) + ((hs >> 4) << 3) + (wsx >> 4);
      int ndx = ((hs & 15) << 4) + (wsx & 15);
      base[tt][reg] = ((size_t)wdx * NHEAD) * NTOK * HD + (size_t)ndx * HD;
    }
#pragma unroll
  for (int nt = 0; nt < 9; ++nt) {
    int col = wave * 144 + nt * 16 + lm;
    float bias = qb[col];
    int sect = col / 192, within = col - sect * 192;
    int head = within >> 5, d = within & 31;
    bf16* dst = (sect == 0) ? Qg : (sect == 1) ? Kg : Vg;
    float scale = (sect == 0) ? SCALE_Q : 1.f;
#pragma unroll
    for (int tt = 0; tt < 2; ++tt)
#pragma unroll
      for (int reg = 0; reg < 4; ++reg) {
        dst[base[tt][reg] + (size_t)head * NTOK * HD + d] =
            f2b((acc[nt][tt][reg] + bias) * scale);
      }
  }
}

// --- K4: windowed attention via MFMA --------------------------------------
// grid = 1536*2 (wh, query-half). block 256 = 4 waves x 32 queries.
// S = Q*K^T (MFMA), full softmax per 16-row tile, P->LDS bf16, O = P*V (MFMA).
__global__ __launch_bounds__(256) void k_attn2(const bf16* __restrict__ Qg,
                                               const bf16* __restrict__ Kg,
                                               const bf16* __restrict__ Vg,
                                               const float* __restrict__ biasQ,
                                               bf16* __restrict__ AO) {
  __shared__ unsigned short PTw[4][16 * PSTR];  // 33,792 B (wave-private P tiles)
  __shared__ unsigned short VT[32 * PSTR];      // 16,896 B (V transposed)
  int wh = blockIdx.x >> 1, half = blockIdx.x & 1;
  int wdx = wh / NHEAD, h = wh - wdx * NHEAD;
  int wl = wdx & 63;
  int wr = wl >> 3, wc = wl & 7;
  int tid = threadIdx.x;
  int wave = tid >> 6, lane = tid & 63;
  int lm = lane & 15, lq = lane >> 4;
  int q0 = half * 128;

  // stage V^T: thread tid handles key row tid
  {
    const uint4* vp = (const uint4*)(Vg + ((size_t)wh * NTOK + tid) * HD);
    uint4 vv[4] = {vp[0], vp[1], vp[2], vp[3]};
#pragma unroll
    for (int i = 0; i < 4; ++i) {
      unsigned arr[4] = {vv[i].x, vv[i].y, vv[i].z, vv[i].w};
#pragma unroll
      for (int j = 0; j < 4; ++j) {
        int d = i * 8 + j * 2;
        VT[d * PSTR + tid]       = (unsigned short)(arr[j] & 0xffffu);
        VT[(d + 1) * PSTR + tid] = (unsigned short)(arr[j] >> 16);
      }
    }
  }
  __syncthreads();

  int wsk = (wc << 4) + lm;                       // lane's key col (w coord)
  int ridk_w = (wsk >= 112) + (wsk >= 120);
  unsigned short* PT = &PTw[wave][0];

  float4v oacc[2][2];
#pragma unroll
  for (int rt = 0; rt < 2; ++rt)
#pragma unroll
    for (int c2 = 0; c2 < 2; ++c2) oacc[rt][c2] = (float4v){0.f, 0.f, 0.f, 0.f};
  float linv[2][4];

#pragma unroll
  for (int rt = 0; rt < 2; ++rt) {
    int qrow = q0 + wave * 32 + rt * 16;
    short8 aq = *(const short8*)(Qg + ((size_t)wh * NTOK + qrow + lm) * HD + lq * 8);
    float4v sacc[16];
#pragma unroll
    for (int ct = 0; ct < 16; ++ct) sacc[ct] = (float4v){0.f, 0.f, 0.f, 0.f};
#pragma unroll
    for (int ct = 0; ct < 16; ++ct) {
      short8 kf = *(const short8*)(Kg + ((size_t)wh * NTOK + ct * 16 + lm) * HD + lq * 8);
      sacc[ct] = __builtin_amdgcn_mfma_f32_16x16x32_bf16(aq, kf, sacc[ct], 0, 0, 0);
    }
    // softmax over 256 keys, rows lq*4+reg of this 16-row tile
#pragma unroll
    for (int reg = 0; reg < 4; ++reg) {
      int nq = qrow + lq * 4 + reg;
      int hsq = (wr << 4) + (nq >> 4), wsq = (wc << 4) + (nq & 15);
      int ridq = ((hsq >= 112) + (hsq >= 120)) * 3 + ((wsq >= 112) + (wsq >= 120));
      const float* bq = biasQ + ((size_t)(h * 256 + nq)) * 256 + lm;
      float sv[16];
      float mx = -1.0e30f;
#pragma unroll
      for (int ct = 0; ct < 16; ++ct) {
        int hsk = (wr << 4) + ct;
        int ridk = ((hsk >= 112) + (hsk >= 120)) * 3 + ridk_w;
        float s = sacc[ct][reg] + bq[ct * 16] + ((ridk != ridq) ? -100.f : 0.f);
        sv[ct] = s;
        mx = fmaxf(mx, s);
      }
#pragma unroll
      for (int off = 1; off < 16; off <<= 1) mx = fmaxf(mx, __shfl_xor(mx, off, 64));
      float l = 0.f;
#pragma unroll
      for (int ct = 0; ct < 16; ++ct) {
        float p = __expf(sv[ct] - mx);
        l += p;
        PT[(lq * 4 + reg) * PSTR + ct * 16 + lm] = f2bu(p);
      }
#pragma unroll
      for (int off = 1; off < 16; off <<= 1) l += __shfl_xor(l, off, 64);
      linv[rt][reg] = 1.f / l;
    }
    // PV for this row tile: A = P rows (wave-private, in-wave LDS ordering)
#pragma unroll
    for (int kb = 0; kb < 8; ++kb) {
      short8 pf = *(const short8*)&PT[lm * PSTR + kb * 32 + lq * 8];
#pragma unroll
      for (int c2 = 0; c2 < 2; ++c2) {
        short8 vf = *(const short8*)&VT[(c2 * 16 + lm) * PSTR + kb * 32 + lq * 8];
        oacc[rt][c2] = __builtin_amdgcn_mfma_f32_16x16x32_bf16(pf, vf, oacc[rt][c2], 0, 0, 0);
      }
    }
  }
  // write AO
#pragma unroll
  for (int rt = 0; rt < 2; ++rt)
#pragma unroll
    for (int c2 = 0; c2 < 2; ++c2) {
      int d = c2 * 16 + lm;
#pragma unroll
      for (int reg = 0; reg < 4; ++reg) {
        int nq = q0 + wave * 32 + rt * 16 + lq * 4 + reg;
        AO[((size_t)wdx * NTOK + nq) * CC + h * HD + d] =
            f2b(oacc[rt][c2][reg] * linv[rt][reg]);
      }
    }
}

// --- K5: proj GEMM via MFMA (N=192, K=192) + shift-reverse + x residual -----
// grid TTOT/32 (win-order rows), block 256 (4 waves). Wave w: cols w*48..+47.
// 2 token-tiles per block: each wP fragment feeds 2 MFMA.
__global__ __launch_bounds__(256) void k_proj2(const bf16* __restrict__ AO,
                                               const bf16* __restrict__ wP,
                                               const float* __restrict__ pb,
                                               const float* __restrict__ x,
                                               float* __restrict__ y) {
  int r0 = blockIdx.x * 32;
  int wave = threadIdx.x >> 6, lane = threadIdx.x & 63;
  int lm = lane & 15, lq = lane >> 4;
  const bf16* arow0 = AO + (size_t)(r0 + lm) * CC + lq * 8;
  const bf16* arow1 = AO + (size_t)(r0 + 16 + lm) * CC + lq * 8;
  float4v acc[3][2];
#pragma unroll
  for (int nt = 0; nt < 3; ++nt)
#pragma unroll
    for (int tt = 0; tt < 2; ++tt) acc[nt][tt] = (float4v){0.f, 0.f, 0.f, 0.f};
#pragma unroll
  for (int ks = 0; ks < 6; ++ks) {
    short8 af0 = *(const short8*)(arow0 + ks * 32);
    short8 af1 = *(const short8*)(arow1 + ks * 32);
#pragma unroll
    for (int nt = 0; nt < 3; ++nt) {
      int col = wave * 48 + nt * 16 + lm;
      short8 bfrag = *(const short8*)(wP + (size_t)col * CC + ks * 32 + lq * 8);
      acc[nt][0] = __builtin_amdgcn_mfma_f32_16x16x32_bf16(af0, bfrag, acc[nt][0], 0, 0, 0);
      acc[nt][1] = __builtin_amdgcn_mfma_f32_16x16x32_bf16(af1, bfrag, acc[nt][1], 0, 0, 0);
    }
  }
  size_t drow[2][4];
#pragma unroll
  for (int tt = 0; tt < 2; ++tt)
#pragma unroll
    for (int reg = 0; reg < 4; ++reg) {
      int r = r0 + tt * 16 + lq * 4 + reg;
      int wdx = r >> 8, n = r & 255;
      int wb = wdx >> 6, wl = wdx & 63;
      int hs = ((wl >> 3) << 4) + (n >> 4);
      int wsx = ((wl & 7) << 4) + (n & 15);
      int gh = (hs + SSH) & 127, gw = (wsx + SSH) & 127;
      drow[tt][reg] = ((size_t)wb * HWPIX + (size_t)gh * WWID + gw) * CC;
    }
#pragma unroll
  for (int nt = 0; nt < 3; ++nt) {
    int col = wave * 48 + nt * 16 + lm;
    float bias = pb[col];
#pragma unroll
    for (int tt = 0; tt < 2; ++tt)
#pragma unroll
      for (int reg = 0; reg < 4; ++reg) {
        y[drow[tt][reg] + col] = x[drow[tt][reg] + col] + acc[nt][tt][reg] + bias;
      }
  }
}

// ---- K6: conv3x3 192->64 + GELU via MFMA implicit GEMM ---------------------
__global__ __launch_bounds__(256) void k_conv1m(const bf16* __restrict__ xn,
                                                const bf16* __restrict__ wT1,
                                                const float* __restrict__ c1b,
                                                bf16* __restrict__ cv1) {
  int bi = blockIdx.x;
  int seg = bi & 1, hh = (bi >> 1) & 127, b = bi >> 8;
  int px0 = seg * 64;
  int wave = threadIdx.x >> 6, lane = threadIdx.x & 63;
  int lm = lane & 15, lq = lane >> 4;
  int oc = wave * 16 + lm;
  float4v acc[4];
#pragma unroll
  for (int t = 0; t < 4; ++t) acc[t] = (float4v){0.f, 0.f, 0.f, 0.f};
#pragma unroll
  for (int tap = 0; tap < 9; ++tap) {
    int kh = tap / 3, kw = tap % 3;
    int gh = hh + kh - 1;
    bool rowok = ((unsigned)gh < 128u);
    const bf16* wrow = wT1 + ((size_t)tap * 64 + oc) * CC + lq * 8;
    const bf16* xrow = xn + ((size_t)b * HWPIX + (size_t)gh * WWID) * CC + lq * 8;
#pragma unroll
    for (int ks = 0; ks < 6; ++ks) {
      short8 bfrag = *(const short8*)(wrow + ks * 32);
#pragma unroll
      for (int t = 0; t < 4; ++t) {
        int px = px0 + t * 16 + lm + kw - 1;
        short8 afrag = ld8z(xrow + (size_t)px * CC + ks * 32,
                            rowok && ((unsigned)px < 128u));
        acc[t] = __builtin_amdgcn_mfma_f32_16x16x32_bf16(afrag, bfrag, acc[t], 0, 0, 0);
      }
    }
  }
  float bias = c1b[oc];
#pragma unroll
  for (int t = 0; t < 4; ++t) {
    int pxb = px0 + t * 16 + lq * 4;
    size_t base = ((size_t)b * HWPIX + (size_t)hh * WWID + pxb) * 64 + oc;
    cv1[base]       = f2b(gelu_exact(acc[t][0] + bias));
    cv1[base + 64]  = f2b(gelu_exact(acc[t][1] + bias));
    cv1[base + 128] = f2b(gelu_exact(acc[t][2] + bias));
    cv1[base + 192] = f2b(gelu_exact(acc[t][3] + bias));
  }
}

// ---- K7: conv3x3 64->192 + bias via MFMA implicit GEMM ---------------------
__global__ __launch_bounds__(256) void k_conv2m(const bf16* __restrict__ cv1,
                                                const bf16* __restrict__ wT2,
                                                const float* __restrict__ c2b,
                                                bf16* __restrict__ cv2) {
  int bi = blockIdx.x;
  int seg = bi & 1, hh = (bi >> 1) & 127, b = bi >> 8;
  int px0 = seg * 64;
  int wave = threadIdx.x >> 6, lane = threadIdx.x & 63;
  int lm = lane & 15, lq = lane >> 4;
  float4v acc[3][4];
#pragma unroll
  for (int nt = 0; nt < 3; ++nt)
#pragma unroll
    for (int t = 0; t < 4; ++t) acc[nt][t] = (float4v){0.f, 0.f, 0.f, 0.f};
#pragma unroll
  for (int tap = 0; tap < 9; ++tap) {
    int kh = tap / 3, kw = tap % 3;
    int gh = hh + kh - 1;
    bool rowok = ((unsigned)gh < 128u);
    const bf16* xrow = cv1 + ((size_t)b * HWPIX + (size_t)gh * WWID) * 64 + lq * 8;
#pragma unroll
    for (int ks = 0; ks < 2; ++ks) {
      short8 bfrag[3];
#pragma unroll
      for (int nt = 0; nt < 3; ++nt) {
        int oc = wave * 48 + nt * 16 + lm;
        bfrag[nt] = *(const short8*)(wT2 + ((size_t)tap * 192 + oc) * 64 + ks * 32 + lq * 8);
      }
#pragma unroll
      for (int t = 0; t < 4; ++t) {
        int px = px0 + t * 16 + lm + kw - 1;
        short8 afrag = ld8z(xrow + (size_t)px * 64 + ks * 32,
                            rowok && ((unsigned)px < 128u));
#pragma unroll
        for (int nt = 0; nt < 3; ++nt)
          acc[nt][t] = __builtin_amdgcn_mfma_f32_16x16x32_bf16(afrag, bfrag[nt], acc[nt][t], 0, 0, 0);
      }
    }
  }
#pragma unroll
  for (int nt = 0; nt < 3; ++nt) {
    int oc = wave * 48 + nt * 16 + lm;
    float bias = c2b[oc];
#pragma unroll
    for (int t = 0; t < 4; ++t) {
      int pxb = px0 + t * 16 + lq * 4;
      size_t base = ((size_t)b * HWPIX + (size_t)hh * WWID + pxb) * CC + oc;
      cv2[base]           = f2b(acc[nt][t][0] + bias);
      cv2[base + CC]      = f2b(acc[nt][t][1] + bias);
      cv2[base + 2 * CC]  = f2b(acc[nt][t][2] + bias);
      cv2[base + 3 * CC]  = f2b(acc[nt][t][3] + bias);
    }
  }
}

// ---------------- K8: global average pool (sum into pooled, pre-zeroed) ----
__global__ __launch_bounds__(192) void k_pool(const bf16* __restrict__ cv2,
                                              float* __restrict__ pooled) {
  int t = threadIdx.x;                        // channel
  int b = blockIdx.x >> 7;
  int pc = blockIdx.x & 127;                  // 128-pixel chunk
  const bf16* base = cv2 + ((size_t)b * HWPIX + (size_t)pc * 128) * CC + t;
  float s = 0.f;
#pragma unroll 4
  for (int p = 0; p < 128; ++p) s += b2f(base[(size_t)p * CC]);
  atomicAdd(&pooled[b * CC + t], s);
}

// ---------------- K9: channel attention weights ----------------
__global__ __launch_bounds__(192) void k_ca(const float* __restrict__ pooled,
                                            const float* __restrict__ w1,
                                            const float* __restrict__ b1,
                                            const float* __restrict__ w2,
                                            const float* __restrict__ b2,
                                            float* __restrict__ ca) {
  __shared__ float pld[CC];
  __shared__ float t1[6];
  int t = threadIdx.x, b = blockIdx.x;
  pld[t] = pooled[b * CC + t] * (1.0f / HWPIX);
  __syncthreads();
  if (t < 6) {
    float s = b1[t];
    for (int c = 0; c < CC; ++c) s += pld[c] * w1[c * 6 + t];
    t1[t] = fmaxf(s, 0.f);
  }
  __syncthreads();
  float s = b2[t];
#pragma unroll
  for (int k = 0; k < 6; ++k) s += t1[k] * w2[k * CC + t];
  ca[b * CC + t] = 1.f / (1.f + __expf(-s));
}

// --- K10: LN2 with conv-branch fold: yn = LN(y + cv2*ca*0.01) bf16 ---------
__global__ __launch_bounds__(256) void k_ln2(const float* __restrict__ y,
                                             const bf16* __restrict__ cv2,
                                             const float* __restrict__ ca,
                                             const float* __restrict__ g2,
                                             const float* __restrict__ b2,
                                             bf16* __restrict__ yn) {
  int wv = threadIdx.x >> 6, lane = threadIdx.x & 63;
  int tok = blockIdx.x * 4 + wv;
  const float* cab = ca + (tok >> 14) * CC;
  size_t row = (size_t)tok * CC;
  float v0 = y[row + lane]       + b2f(cv2[row + lane])       * cab[lane]       * CONV_SC;
  float v1 = y[row + lane + 64]  + b2f(cv2[row + lane + 64])  * cab[lane + 64]  * CONV_SC;
  float v2 = y[row + lane + 128] + b2f(cv2[row + lane + 128]) * cab[lane + 128] * CONV_SC;
  float s = v0 + v1 + v2, ss = v0 * v0 + v1 * v1 + v2 * v2;
#pragma unroll
  for (int off = 1; off < 64; off <<= 1) {
    s += __shfl_xor(s, off, 64);
    ss += __shfl_xor(ss, off, 64);
  }
  float mean = s * (1.0f / CC);
  float rstd = rsqrtf(ss * (1.0f / CC) - mean * mean + 1e-5f);
  yn[row + lane]       = f2b((v0 - mean) * rstd * g2[lane]       + b2[lane]);
  yn[row + lane + 64]  = f2b((v1 - mean) * rstd * g2[lane + 64]  + b2[lane + 64]);
  yn[row + lane + 128] = f2b((v2 - mean) * rstd * g2[lane + 128] + b2[lane + 128]);
}

// --- K11a: fc1 weight-stationary: h = GELU(yn @ fc1 + b) --------------------
// grid 512 = 4 col-panels (cg) x 128 token-blocks (tb, 512 tokens).
// Panel wF1[cg*192..+192)[192] = 73,728 B is CONTIGUOUS in wF1 -> staged once
// by a linear global_load_lds memcpy (source XOR-swizzled at 16B granularity
// with (row&7) so per-row reads spread over 8 bank-groups; LDS stays linear
// per rule #21). Wave's 18 weight frags hoisted to 72 VGPR, then a barrier-
// free loop over 32 token tiles: 6 yn loads + 18 MFMA + GELU + 8B h stores.
// Swapped-operand MFMA: C rows = weight cols -> 4 consecutive n per lane.
__global__ __launch_bounds__(256, 2) void k_fc1ws(const bf16* __restrict__ yn,
                                                  const bf16* __restrict__ wF1,
                                                  const float* __restrict__ fb1,
                                                  bf16* __restrict__ h) {
  __shared__ unsigned short wl[192 * 192];   // 73,728 B
  int cg = blockIdx.x & 3, tb = blockIdx.x >> 2;
  int tid = threadIdx.x;
  int wave = tid >> 6, lane = tid & 63;
  int lm = lane & 15, lq = lane >> 4;

  const char* src = (const char*)wF1 + (size_t)cg * 73728;
#pragma unroll
  for (int j = 0; j < 18; ++j) {
    int ci = j * 256 + tid;                  // 16B-chunk index 0..4607
    int r = ci / 24, c = ci - r * 24;        // row 0..191, chunk 0..23
    glds16(src + (size_t)r * 384 + ((c ^ (r & 7)) << 4),
           (char*)wl + (size_t)(j * 256 + wave * 64) * 16);
  }
  __syncthreads();

  // hoist wave's B-frags (cols wave*48 + nt*16 + lm) -- one-time LDS reads
  short8 wfr[3][6];
#pragma unroll
  for (int nt = 0; nt < 3; ++nt) {
    int rl = wave * 48 + nt * 16 + lm;
#pragma unroll
    for (int ks = 0; ks < 6; ++ks)
      wfr[nt][ks] = *(const short8*)&wl[rl * 192 + (((ks * 4 + lq) ^ (rl & 7)) << 3)];
  }
  float4 b4[3];
#pragma unroll
  for (int nt = 0; nt < 3; ++nt)
    b4[nt] = *(const float4*)(fb1 + cg * 192 + wave * 48 + nt * 16 + lq * 4);

  int tok0b = tb * 512;
#pragma unroll 2
  for (int t = 0; t < 32; ++t) {
    int tok0 = tok0b + t * 16;
    const bf16* arow = yn + (size_t)(tok0 + lm) * CC + lq * 8;
    float4v acc[3];
#pragma unroll
    for (int nt = 0; nt < 3; ++nt) acc[nt] = (float4v){0.f, 0.f, 0.f, 0.f};
#pragma unroll
    for (int ks = 0; ks < 6; ++ks) {
      short8 tf = *(const short8*)(arow + ks * 32);
#pragma unroll
      for (int nt = 0; nt < 3; ++nt)
        acc[nt] = __builtin_amdgcn_mfma_f32_16x16x32_bf16(wfr[nt][ks], tf, acc[nt], 0, 0, 0);
    }
    bf16* hrow = h + (size_t)(tok0 + lm) * 768 + cg * 192 + wave * 48 + lq * 4;
#pragma unroll
    for (int nt = 0; nt < 3; ++nt) {
      unsigned short u0 = f2bu(gelu_exact(acc[nt][0] + b4[nt].x));
      unsigned short u1 = f2bu(gelu_exact(acc[nt][1] + b4[nt].y));
      unsigned short u2 = f2bu(gelu_exact(acc[nt][2] + b4[nt].z));
      unsigned short u3 = f2bu(gelu_exact(acc[nt][3] + b4[nt].w));
      uint2 pk;
      pk.x = (unsigned)u0 | ((unsigned)u1 << 16);
      pk.y = (unsigned)u2 | ((unsigned)u3 << 16);
      *(uint2*)(hrow + nt * 16) = pk;
    }
  }
}

// --- K11b: fc2 weight-stationary + residual epilogue ------------------------
// grid 512 = 4 col-panels (48 cols) x 128 token-blocks (512 tokens).
// Panel wF2[cg*48..+48)[768] = 73,728 B contiguous -> staged once (same
// swizzled linear memcpy). Barrier-free main loop: wave owns 8 token tiles
// as 4 pairs; per ks: 2 h-loads (global) + 3 swizzled ds_reads + 6 MFMA.
__global__ __launch_bounds__(256, 2) void k_fc2ws(const bf16* __restrict__ h,
                                                  const bf16* __restrict__ wF2,
                                                  const float* __restrict__ fb2,
                                                  const float* __restrict__ y,
                                                  const bf16* __restrict__ cv2,
                                                  const float* __restrict__ ca,
                                                  float* __restrict__ out) {
  __shared__ unsigned short wl[48 * 768];    // 73,728 B
  int cg = blockIdx.x & 3, tb = blockIdx.x >> 2;
  int tid = threadIdx.x;
  int wave = tid >> 6, lane = tid & 63;
  int lm = lane & 15, lq = lane >> 4;

  const char* src = (const char*)wF2 + (size_t)cg * 73728;
#pragma unroll
  for (int j = 0; j < 18; ++j) {
    int ci = j * 256 + tid;                  // 16B-chunk index 0..4607
    int r = ci / 96, c = ci - r * 96;        // row 0..47, chunk 0..95
    glds16(src + (size_t)r * 1536 + ((c ^ (r & 7)) << 4),
           (char*)wl + (size_t)(j * 256 + wave * 64) * 16);
  }
  __syncthreads();

  int colb = cg * 48;
  const float* cab = ca + ((tb * 512) >> 14) * CC;
  float bias[3], cas[3];
#pragma unroll
  for (int nt = 0; nt < 3; ++nt) {
    int col = colb + nt * 16 + lm;
    bias[nt] = fb2[col];
    cas[nt] = cab[col] * CONV_SC;
  }

  for (int pp = 0; pp < 4; ++pp) {
    int t0 = tb * 512 + (wave * 8 + pp * 2) * 16;
    const bf16* ar0 = h + (size_t)(t0 + lm) * 768 + lq * 8;
    const bf16* ar1 = h + (size_t)(t0 + 16 + lm) * 768 + lq * 8;
    float4v acc[2][3];
#pragma unroll
    for (int tt = 0; tt < 2; ++tt)
#pragma unroll
      for (int nt = 0; nt < 3; ++nt) acc[tt][nt] = (float4v){0.f, 0.f, 0.f, 0.f};
#pragma unroll
    for (int ks = 0; ks < 24; ++ks) {
      short8 a0 = *(const short8*)(ar0 + ks * 32);
      short8 a1 = *(const short8*)(ar1 + ks * 32);
#pragma unroll
      for (int nt = 0; nt < 3; ++nt) {
        int rl = nt * 16 + lm;
        short8 bf = *(const short8*)&wl[rl * 768 + (((ks * 4 + lq) ^ (rl & 7)) << 3)];
        acc[0][nt] = __builtin_amdgcn_mfma_f32_16x16x32_bf16(a0, bf, acc[0][nt], 0, 0, 0);
        acc[1][nt] = __builtin_amdgcn_mfma_f32_16x16x32_bf16(a1, bf, acc[1][nt], 0, 0, 0);
      }
    }
#pragma unroll
    for (int tt = 0; tt < 2; ++tt)
#pragma unroll
      for (int nt = 0; nt < 3; ++nt) {
        int col = colb + nt * 16 + lm;
#pragma unroll
        for (int reg = 0; reg < 4; ++reg) {
          int tok = t0 + tt * 16 + lq * 4 + reg;
          size_t idx = (size_t)tok * CC + col;
          out[idx] = y[idx] + b2f(cv2[idx]) * cas[nt] + acc[tt][nt][reg] + bias[nt];
        }
      }
  }
}

extern "C" void kernel_launch(void* const* d_in, const int* in_sizes, int n_in,
                              void* d_out, int out_size, void* d_ws, size_t ws_size,
                              hipStream_t stream) {
  const float* x      = (const float*)d_in[0];
  const float* qkv_w  = (const float*)d_in[1];
  const float* qkv_b  = (const float*)d_in[2];
  const float* proj_w = (const float*)d_in[3];
  const float* proj_b = (const float*)d_in[4];
  const float* rpb    = (const float*)d_in[5];
  const float* n1w    = (const float*)d_in[6];
  const float* n1b    = (const float*)d_in[7];
  const float* n2w    = (const float*)d_in[8];
  const float* n2b    = (const float*)d_in[9];
  const float* c1w    = (const float*)d_in[10];
  const float* c1b    = (const float*)d_in[11];
  const float* c2w    = (const float*)d_in[12];
  const float* c2b    = (const float*)d_in[13];
  const float* ca1w   = (const float*)d_in[14];
  const float* ca1b   = (const float*)d_in[15];
  const float* ca2w   = (const float*)d_in[16];
  const float* ca2b   = (const float*)d_in[17];
  const float* fc1w   = (const float*)d_in[18];
  const float* fc1b   = (const float*)d_in[19];
  const float* fc2w   = (const float*)d_in[20];
  const float* fc2b   = (const float*)d_in[21];
  const int*   rpi    = (const int*)d_in[22];
  (void)in_sizes; (void)n_in; (void)out_size; (void)ws_size;

  // ---- workspace layout: peak ~212.6 MB (< 256 MiB) ----
  char* wsb = (char*)d_ws;
  bf16*  xn    = (bf16*)(wsb + 0);            // 25,165,824
  bf16*  yn    = (bf16*)(wsb + 0);            // alias xn (dead after conv1m)
  float* biasQ = (float*)(wsb + 25165824);    //  1,572,864
  bf16*  Qg    = (bf16*)(wsb + 26738688);     // 25,165,824
  bf16*  Kg    = (bf16*)(wsb + 51904512);     // 25,165,824
  bf16*  Vg    = (bf16*)(wsb + 77070336);     // 25,165,824
  bf16*  AO    = (bf16*)(wsb + 102236160);    // 25,165,824
  bf16*  hbuf  = (bf16*)(wsb + 26738688);     // 100,663,296 alias Qg..AO (dead after proj2)
  float* y     = (float*)(wsb + 127401984);   // 50,331,648
  bf16*  cv1   = (bf16*)(wsb + 177733632);    //  8,388,608
  bf16*  cv2   = (bf16*)(wsb + 186122240);    // 25,165,824
  float* pool  = (float*)(wsb + 211288064);   //      3,072
  float* cavec = (float*)(wsb + 211291136);   //      3,072
  bf16*  wT1   = (bf16*)(wsb + 211294208);    //    221,184  [9][64][192]
  bf16*  wT2   = (bf16*)(wsb + 211515392);    //    221,184  [9][192][64]
  bf16*  wF1   = (bf16*)(wsb + 211736576);    //    294,912  [768][192]
  bf16*  wF2   = (bf16*)(wsb + 212031488);    //    294,912  [192][768]
  bf16*  wQv   = (bf16*)(wsb + 212326400);    //    221,184  [576][192]
  bf16*  wP    = (bf16*)(wsb + 212547584);    //     73,728  [192][192]
  float* out   = (float*)d_out;               // end 212,621,312

  k_ln1<<<TTOT / 4, 256, 0, stream>>>(x, n1w, n1b, xn);
  k_biasq<<<NHEAD * NTOK, 256, 0, stream>>>(rpi, rpb, biasQ);
  k_wprep<<<432, 256, 0, stream>>>(c1w, c2w, wT1, wT2);
  k_wprep2<<<576, 256, 0, stream>>>(fc1w, fc2w, wF1, wF2);
  k_wprep3<<<576, 256, 0, stream>>>(qkv_w, proj_w, wQv, wP);
  k_qkvg2<<<TTOT / 32, 256, 0, stream>>>(xn, wQv, qkv_b, Qg, Kg, Vg);
  k_attn2<<<BB * 64 * NHEAD * 2, 256, 0, stream>>>(Qg, Kg, Vg, biasQ, AO);
  k_proj2<<<TTOT / 32, 256, 0, stream>>>(AO, wP, proj_b, x, y);
  k_conv1m<<<1024, 256, 0, stream>>>(xn, wT1, c1b, cv1);
  k_conv2m<<<1024, 256, 0, stream>>>(cv1, wT2, c2b, cv2);
  hipMemsetAsync(pool, 0, BB * CC * sizeof(float), stream);
  k_pool<<<512, 192, 0, stream>>>(cv2, pool);
  k_ca<<<BB, 192, 0, stream>>>(pool, ca1w, ca1b, ca2w, ca2b, cavec);
  k_ln2<<<TTOT / 4, 256, 0, stream>>>(y, cv2, cavec, n2w, n2b, yn);
  k_fc1ws<<<512, 256, 0, stream>>>(yn, wF1, fc1b, hbuf);
  k_fc2ws<<<512, 256, 0, stream>>>(hbuf, wF2, fc2b, y, cv2, cavec, out);
}